// Round 1
// baseline (529.830 us; speedup 1.0000x reference)
//
#include <hip/hip_runtime.h>
#include <hip/hip_bf16.h>

#define N_Q   10000
#define N_CAM 6
#define HIMG  60
#define WIMG  100

// ---------------------------------------------------------------------------
// Kernel 1: transpose image feats (6,256,60,100) -> (6,60,100,256)  [NHWC]
// so a bilinear corner fetch for one head = 32 consecutive floats (128B).
// ---------------------------------------------------------------------------
__global__ __launch_bounds__(256) void transpose_feats_k(
    const float* __restrict__ in, float* __restrict__ out) {
  int pix = blockIdx.x;            // cam*6000 + y*100 + x
  int cam = pix / 6000;
  int yx  = pix - cam * 6000;
  int c   = threadIdx.x;           // 0..255
  out[pix * 256 + c] = in[(cam * 256 + c) * 6000 + yx];
}

// ---------------------------------------------------------------------------
// Kernel 2: fp32 GEMM  C[M,N] = A[M,256] @ B[256,N] + bias, optional epilogue
// mode 0: none   mode 1: tanh(v)*0.12  (offset head)
// 64x64 tile, 256 threads, 4x4 microtile, K-tiles of 16 staged in LDS.
// ---------------------------------------------------------------------------
#define TM 64
#define TN 64
#define KT 16

__global__ __launch_bounds__(256) void gemm_bias(
    const float* __restrict__ A,    // M x 256 row-major
    const float* __restrict__ B,    // 256 x N row-major
    const float* __restrict__ bias, // N
    float* __restrict__ C,          // M x N
    int M, int N, int mode) {
  __shared__ float As[KT][TM];
  __shared__ float Bs[KT][TN];
  const int K = 256;
  const int bm = blockIdx.x * TM;
  const int bn = blockIdx.y * TN;
  const int tid = threadIdx.x;
  const int tx = tid & 15, ty = tid >> 4;

  float acc[4][4] = {};

  for (int k0 = 0; k0 < K; k0 += KT) {
    // A tile: 64 rows x 16 k  (float4 per thread), store transposed
    {
      int m  = tid >> 2;
      int kk = (tid & 3) * 4;
      int row = bm + m;
      float4 v = make_float4(0.f, 0.f, 0.f, 0.f);
      if (row < M)
        v = *reinterpret_cast<const float4*>(&A[row * K + k0 + kk]);
      As[kk + 0][m] = v.x; As[kk + 1][m] = v.y;
      As[kk + 2][m] = v.z; As[kk + 3][m] = v.w;
    }
    // B tile: 16 k x 64 n (float4 per thread), coalesced
    {
      int kk = tid >> 4;
      int nn = (tid & 15) * 4;
      float4 v = *reinterpret_cast<const float4*>(&B[(k0 + kk) * N + bn + nn]);
      Bs[kk][nn + 0] = v.x; Bs[kk][nn + 1] = v.y;
      Bs[kk][nn + 2] = v.z; Bs[kk][nn + 3] = v.w;
    }
    __syncthreads();
#pragma unroll
    for (int k = 0; k < KT; ++k) {
      float a[4], b[4];
#pragma unroll
      for (int i = 0; i < 4; ++i) a[i] = As[k][ty * 4 + i];
#pragma unroll
      for (int j = 0; j < 4; ++j) b[j] = Bs[k][tx * 4 + j];
#pragma unroll
      for (int i = 0; i < 4; ++i)
#pragma unroll
        for (int j = 0; j < 4; ++j)
          acc[i][j] = fmaf(a[i], b[j], acc[i][j]);
    }
    __syncthreads();
  }

#pragma unroll
  for (int i = 0; i < 4; ++i) {
    int row = bm + ty * 4 + i;
    if (row >= M) continue;
    int col = bn + tx * 4;
    float4 o;
    float* po = &o.x;
#pragma unroll
    for (int j = 0; j < 4; ++j) {
      float v = acc[i][j] + bias[col + j];
      if (mode == 1) v = tanhf(v) * 0.12f;
      po[j] = v;
    }
    *reinterpret_cast<float4*>(&C[row * N + col]) = o;
  }
}

// ---------------------------------------------------------------------------
// Kernel 3: per-query deformable sampling + masked softmax + cam fusion.
// Block = 1 query, 256 threads: thread (h = tid>>5, c = tid&31) owns
// fused[n][h*32+c]. Softmax over 16 pts per head via width-16 shfl reduce.
// ---------------------------------------------------------------------------
__global__ __launch_bounds__(256) void sample_fuse(
    const float* __restrict__ ft,     // (6,60,100,256) NHWC
    const float* __restrict__ offs,   // (N,256) = [h][pp][pn][xy]
    const float* __restrict__ wlog,   // (N,128) = [h][p]
    const float* __restrict__ refp,   // (6,N,4,2)
    const int*   __restrict__ mask,   // (6,N,4) 0/1
    float* __restrict__ fused) {      // (N,256)
  const int n   = blockIdx.x;
  const int tid = threadIdx.x;
  const int h   = tid >> 5;
  const int c   = tid & 31;

  __shared__ float loff[256];
  __shared__ float sw[128];
  __shared__ float sref[8];
  __shared__ int   svis[4];

  loff[tid] = offs[n * 256 + tid];
  float logit = (tid < 128) ? wlog[n * 128 + tid] : 0.f;

  float acc = 0.f;
  int   cnt = 0;

  for (int cam = 0; cam < N_CAM; ++cam) {
    __syncthreads();   // protect sref/svis/sw from previous iteration readers
    if (tid < 4) svis[tid] = mask[(cam * N_Q + n) * 4 + tid];
    if (tid < 8) sref[tid] = refp[(cam * N_Q + n) * 8 + tid];
    __syncthreads();
    const int hv = svis[0] | svis[1] | svis[2] | svis[3];
    if (!hv) continue;
    cnt++;

    // masked softmax over 16 points per head (threads 0..127)
    if (tid < 128) {
      const int p   = tid & 15;
      const int vis = svis[p >> 2];
      float val = vis ? logit : -1e30f;
#pragma unroll
      for (int m = 8; m >= 1; m >>= 1)
        val = fmaxf(val, __shfl_xor(val, m, 16));
      float e = vis ? __expf(logit - val) : 0.f;
      float s = e;
#pragma unroll
      for (int m = 8; m >= 1; m >>= 1)
        s += __shfl_xor(s, m, 16);
      sw[tid] = e / fmaxf(s, 1e-6f);
    }
    __syncthreads();

    // bilinear sampling: 16 points, 4 corners, 32 channels per head
#pragma unroll
    for (int p = 0; p < 16; ++p) {
      const float w = sw[h * 16 + p];
      if (w > 0.f) {                    // uniform per 32-lane group
        const int pp = p >> 2;
        const float lx = sref[pp * 2 + 0] + loff[h * 32 + p * 2 + 0];
        const float ly = sref[pp * 2 + 1] + loff[h * 32 + p * 2 + 1];
        const float x = lx * (float)WIMG - 0.5f;
        const float y = ly * (float)HIMG - 0.5f;
        const float x0f = floorf(x), y0f = floorf(y);
        const float wx = x - x0f, wy = y - y0f;
        const int x0 = (int)x0f, y0 = (int)y0f;
        float sampv = 0.f;
#pragma unroll
        for (int dy = 0; dy < 2; ++dy) {
          const int yi = y0 + dy;
          if (yi < 0 || yi >= HIMG) continue;
          const float wyv = dy ? wy : 1.f - wy;
#pragma unroll
          for (int dx = 0; dx < 2; ++dx) {
            const int xi = x0 + dx;
            if (xi < 0 || xi >= WIMG) continue;
            const float wxv = dx ? wx : 1.f - wx;
            sampv = fmaf(ft[((cam * HIMG + yi) * WIMG + xi) * 256 + h * 32 + c],
                         wxv * wyv, sampv);
          }
        }
        acc = fmaf(sampv, w, acc);
      }
    }
  }

  const float inv = (cnt > 0) ? (1.f / (float)cnt) : 1.f;
  fused[n * 256 + tid] = acc * inv;
}

// ---------------------------------------------------------------------------
extern "C" void kernel_launch(void* const* d_in, const int* in_sizes, int n_in,
                              void* d_out, int out_size, void* d_ws, size_t ws_size,
                              hipStream_t stream) {
  const float* query = (const float*)d_in[0];   // (1,10000,256)
  const float* feats = (const float*)d_in[1];   // (1,6,256,60,100)
  const float* refp  = (const float*)d_in[2];   // (1,6,10000,4,2)
  const int*   mask  = (const int*)d_in[3];     // (1,6,10000,4) bool->int32
  const float* oW    = (const float*)d_in[4];   // (256,256)
  const float* ob    = (const float*)d_in[5];   // (256,)
  const float* wW    = (const float*)d_in[6];   // (256,128)
  const float* wb    = (const float*)d_in[7];   // (128,)
  const float* outW  = (const float*)d_in[8];   // (256,256)
  const float* outb  = (const float*)d_in[9];   // (256,)
  float* out = (float*)d_out;

  float* ws    = (float*)d_ws;
  float* ft    = ws;                        // 6*6000*256   = 9,216,000
  float* offs  = ft + 6 * 6000 * 256;       // 10000*256    = 2,560,000
  float* wlog  = offs + N_Q * 256;          // 10000*128    = 1,280,000
  float* fusedb= wlog + N_Q * 128;          // 10000*256    = 2,560,000

  transpose_feats_k<<<N_CAM * HIMG * WIMG, 256, 0, stream>>>(feats, ft);

  dim3 gOff((N_Q + TM - 1) / TM, 256 / TN);
  gemm_bias<<<gOff, 256, 0, stream>>>(query, oW, ob, offs, N_Q, 256, 1);

  dim3 gLog((N_Q + TM - 1) / TM, 128 / TN);
  gemm_bias<<<gLog, 256, 0, stream>>>(query, wW, wb, wlog, N_Q, 128, 0);

  sample_fuse<<<N_Q, 256, 0, stream>>>(ft, offs, wlog, refp, mask, fusedb);

  dim3 gOut((N_Q + TM - 1) / TM, 256 / TN);
  gemm_bias<<<gOut, 256, 0, stream>>>(fusedb, outW, outb, out, N_Q, 256, 0);
}

// Round 2
// 292.340 us; speedup vs baseline: 1.8124x; 1.8124x over previous
//
#include <hip/hip_runtime.h>
#include <hip/hip_bf16.h>

#define N_Q   10000
#define N_CAM 6
#define HIMG  60
#define WIMG  100

// ---------------------------------------------------------------------------
// Kernel 1: transpose+convert image feats (6,256,60,100) fp32 -> (6,60,100,256)
// bf16 NHWC. One bilinear corner fetch for one head = 32 bf16 = 64B.
// ---------------------------------------------------------------------------
__global__ __launch_bounds__(256) void transpose_feats_k(
    const float* __restrict__ in, __hip_bfloat16* __restrict__ out) {
  int pix = blockIdx.x;            // cam*6000 + y*100 + x
  int cam = pix / 6000;
  int yx  = pix - cam * 6000;
  int c   = threadIdx.x;           // 0..255
  out[pix * 256 + c] = __float2bfloat16(in[(cam * 256 + c) * 6000 + yx]);
}

// ---------------------------------------------------------------------------
// Kernel 2: fp32 GEMM  C[M,N] = A[M,256] @ B[256,N] + bias, optional epilogue
// mode 0: none   mode 1: tanh(v)*0.12  (offset head)
// ---------------------------------------------------------------------------
#define TM 64
#define TN 64
#define KT 16

__global__ __launch_bounds__(256) void gemm_bias(
    const float* __restrict__ A,    // M x 256 row-major
    const float* __restrict__ B,    // 256 x N row-major
    const float* __restrict__ bias, // N
    float* __restrict__ C,          // M x N
    int M, int N, int mode) {
  __shared__ float As[KT][TM];
  __shared__ float Bs[KT][TN];
  const int K = 256;
  const int bm = blockIdx.x * TM;
  const int bn = blockIdx.y * TN;
  const int tid = threadIdx.x;
  const int tx = tid & 15, ty = tid >> 4;

  float acc[4][4] = {};

  for (int k0 = 0; k0 < K; k0 += KT) {
    {
      int m  = tid >> 2;
      int kk = (tid & 3) * 4;
      int row = bm + m;
      float4 v = make_float4(0.f, 0.f, 0.f, 0.f);
      if (row < M)
        v = *reinterpret_cast<const float4*>(&A[row * K + k0 + kk]);
      As[kk + 0][m] = v.x; As[kk + 1][m] = v.y;
      As[kk + 2][m] = v.z; As[kk + 3][m] = v.w;
    }
    {
      int kk = tid >> 4;
      int nn = (tid & 15) * 4;
      float4 v = *reinterpret_cast<const float4*>(&B[(k0 + kk) * N + bn + nn]);
      Bs[kk][nn + 0] = v.x; Bs[kk][nn + 1] = v.y;
      Bs[kk][nn + 2] = v.z; Bs[kk][nn + 3] = v.w;
    }
    __syncthreads();
#pragma unroll
    for (int k = 0; k < KT; ++k) {
      float a[4], b[4];
#pragma unroll
      for (int i = 0; i < 4; ++i) a[i] = As[k][ty * 4 + i];
#pragma unroll
      for (int j = 0; j < 4; ++j) b[j] = Bs[k][tx * 4 + j];
#pragma unroll
      for (int i = 0; i < 4; ++i)
#pragma unroll
        for (int j = 0; j < 4; ++j)
          acc[i][j] = fmaf(a[i], b[j], acc[i][j]);
    }
    __syncthreads();
  }

#pragma unroll
  for (int i = 0; i < 4; ++i) {
    int row = bm + ty * 4 + i;
    if (row >= M) continue;
    int col = bn + tx * 4;
    float4 o;
    float* po = &o.x;
#pragma unroll
    for (int j = 0; j < 4; ++j) {
      float v = acc[i][j] + bias[col + j];
      if (mode == 1) v = tanhf(v) * 0.12f;
      po[j] = v;
    }
    *reinterpret_cast<float4*>(&C[row * N + col]) = o;
  }
}

// ---------------------------------------------------------------------------
// Kernel 3: deformable sampling + masked softmax + cam fusion.
// Block = 2 queries x 128 threads. Thread t (within query): h=t>>4, cp=t&15
// owns channels {2cp, 2cp+1} of head h (one dword = 2 bf16 per corner load).
// Waves are query-uniform -> pillar-visibility branches are scalar.
// Per visible pillar: 4 points x 4 corners = 16 independent loads in flight.
// ---------------------------------------------------------------------------
__device__ __forceinline__ float bf16lo(unsigned int u) {
  return __uint_as_float(u << 16);
}
__device__ __forceinline__ float bf16hi(unsigned int u) {
  return __uint_as_float(u & 0xffff0000u);
}

__global__ __launch_bounds__(256) void sample_fuse(
    const __hip_bfloat16* __restrict__ ft, // (6,60,100,256) NHWC bf16
    const float* __restrict__ offs,   // (N,256) = [h][pp][pn][xy]
    const float* __restrict__ wlog,   // (N,128) = [h][p]
    const float* __restrict__ refp,   // (6,N,4,2)
    const int*   __restrict__ mask,   // (6,N,4) 0/1
    float* __restrict__ fused) {      // (N,256)
  const int tid = threadIdx.x;
  const int sub = tid >> 7;          // which of the 2 queries
  const int t   = tid & 127;
  const int n   = blockIdx.x * 2 + sub;
  const int h   = t >> 4;

  __shared__ float loff[2][256];
  __shared__ float sw[2][128];
  __shared__ float sref[2][8];
  __shared__ int   svis[2][4];

  loff[sub][t]       = offs[n * 256 + t];
  loff[sub][t + 128] = offs[n * 256 + t + 128];
  const float logit = wlog[n * 128 + t];

  const unsigned int* ftu = reinterpret_cast<const unsigned int*>(ft);

  float acc0 = 0.f, acc1 = 0.f;
  int cnt = 0;

  for (int cam = 0; cam < N_CAM; ++cam) {
    __syncthreads();   // protect smem from previous iteration readers
    if (t < 4) svis[sub][t] = mask[(cam * N_Q + n) * 4 + t];
    if (t < 8) sref[sub][t] = refp[(cam * N_Q + n) * 8 + t];
    __syncthreads();
    if (!(svis[sub][0] | svis[sub][1] | svis[sub][2] | svis[sub][3])) continue;
    cnt++;

    // masked softmax over 16 points; this thread handles (h=t>>4, p=t&15)
    {
      const int p   = t & 15;
      const int vis = svis[sub][p >> 2];
      float val = vis ? logit : -1e30f;
#pragma unroll
      for (int m = 8; m >= 1; m >>= 1)
        val = fmaxf(val, __shfl_xor(val, m, 16));
      float e = vis ? __expf(logit - val) : 0.f;
      float s = e;
#pragma unroll
      for (int m = 8; m >= 1; m >>= 1)
        s += __shfl_xor(s, m, 16);
      sw[sub][t] = e / fmaxf(s, 1e-6f);
    }
    __syncthreads();

    const int cambase = cam * (HIMG * WIMG) * 128;  // in dword units
#pragma unroll
    for (int pp = 0; pp < 4; ++pp) {
      if (!svis[sub][pp]) continue;   // wave-uniform scalar branch
      const float rx = sref[sub][pp * 2 + 0];
      const float ry = sref[sub][pp * 2 + 1];
#pragma unroll
      for (int pn = 0; pn < 4; ++pn) {
        const int p = pp * 4 + pn;
        const float w  = sw[sub][h * 16 + p];
        const float x = fmaf(rx + loff[sub][h * 32 + p * 2 + 0], (float)WIMG, -0.5f);
        const float y = fmaf(ry + loff[sub][h * 32 + p * 2 + 1], (float)HIMG, -0.5f);
        const float x0f = floorf(x), y0f = floorf(y);
        const float wx = x - x0f, wy = y - y0f;
        const int x0 = (int)x0f, y0 = (int)y0f;
        const int x1 = x0 + 1, y1 = y0 + 1;
        const float mx0 = (x0 >= 0 && x0 < WIMG) ? 1.f : 0.f;
        const float mx1 = (x1 >= 0 && x1 < WIMG) ? 1.f : 0.f;
        const float my0 = (y0 >= 0 && y0 < HIMG) ? 1.f : 0.f;
        const float my1 = (y1 >= 0 && y1 < HIMG) ? 1.f : 0.f;
        const int xc0 = min(max(x0, 0), WIMG - 1);
        const int xc1 = min(max(x1, 0), WIMG - 1);
        const int yc0 = min(max(y0, 0), HIMG - 1);
        const int yc1 = min(max(y1, 0), HIMG - 1);
        const float w00 = (1.f - wx) * (1.f - wy) * mx0 * my0 * w;
        const float w10 = wx * (1.f - wy) * mx1 * my0 * w;
        const float w01 = (1.f - wx) * wy * mx0 * my1 * w;
        const float w11 = wx * wy * mx1 * my1 * w;
        const unsigned int u00 = ftu[cambase + (yc0 * WIMG + xc0) * 128 + t];
        const unsigned int u10 = ftu[cambase + (yc0 * WIMG + xc1) * 128 + t];
        const unsigned int u01 = ftu[cambase + (yc1 * WIMG + xc0) * 128 + t];
        const unsigned int u11 = ftu[cambase + (yc1 * WIMG + xc1) * 128 + t];
        acc0 = fmaf(bf16lo(u00), w00, acc0);
        acc0 = fmaf(bf16lo(u10), w10, acc0);
        acc0 = fmaf(bf16lo(u01), w01, acc0);
        acc0 = fmaf(bf16lo(u11), w11, acc0);
        acc1 = fmaf(bf16hi(u00), w00, acc1);
        acc1 = fmaf(bf16hi(u10), w10, acc1);
        acc1 = fmaf(bf16hi(u01), w01, acc1);
        acc1 = fmaf(bf16hi(u11), w11, acc1);
      }
    }
  }

  const float inv = (cnt > 0) ? (1.f / (float)cnt) : 1.f;
  float2 o = make_float2(acc0 * inv, acc1 * inv);
  reinterpret_cast<float2*>(fused)[n * 128 + t] = o;  // fused[n*256 + 2t]
}

// ---------------------------------------------------------------------------
extern "C" void kernel_launch(void* const* d_in, const int* in_sizes, int n_in,
                              void* d_out, int out_size, void* d_ws, size_t ws_size,
                              hipStream_t stream) {
  const float* query = (const float*)d_in[0];   // (1,10000,256)
  const float* feats = (const float*)d_in[1];   // (1,6,256,60,100)
  const float* refp  = (const float*)d_in[2];   // (1,6,10000,4,2)
  const int*   mask  = (const int*)d_in[3];     // (1,6,10000,4) bool->int32
  const float* oW    = (const float*)d_in[4];   // (256,256)
  const float* ob    = (const float*)d_in[5];   // (256,)
  const float* wW    = (const float*)d_in[6];   // (256,128)
  const float* wb    = (const float*)d_in[7];   // (128,)
  const float* outW  = (const float*)d_in[8];   // (256,256)
  const float* outb  = (const float*)d_in[9];   // (256,)
  float* out = (float*)d_out;

  char* wsb = (char*)d_ws;
  __hip_bfloat16* ft = (__hip_bfloat16*)wsb;                    // 6*6000*256 bf16 = 18.4 MB
  float* offs   = (float*)(wsb + (size_t)6 * 6000 * 256 * 2);   // 10000*256 f32
  float* wlog   = offs + (size_t)N_Q * 256;                     // 10000*128 f32
  float* fusedb = wlog + (size_t)N_Q * 128;                     // 10000*256 f32

  transpose_feats_k<<<N_CAM * HIMG * WIMG, 256, 0, stream>>>(feats, ft);

  dim3 gOff((N_Q + TM - 1) / TM, 256 / TN);
  gemm_bias<<<gOff, 256, 0, stream>>>(query, oW, ob, offs, N_Q, 256, 1);

  dim3 gLog((N_Q + TM - 1) / TM, 128 / TN);
  gemm_bias<<<gLog, 256, 0, stream>>>(query, wW, wb, wlog, N_Q, 128, 0);

  sample_fuse<<<N_Q / 2, 256, 0, stream>>>(ft, offs, wlog, refp, mask, fusedb);

  dim3 gOut((N_Q + TM - 1) / TM, 256 / TN);
  gemm_bias<<<gOut, 256, 0, stream>>>(fusedb, outW, outb, out, N_Q, 256, 0);
}

// Round 3
// 231.871 us; speedup vs baseline: 2.2850x; 1.2608x over previous
//
#include <hip/hip_runtime.h>
#include <hip/hip_bf16.h>

#define N_Q   10000
#define N_CAM 6
#define HIMG  60
#define WIMG  100
#define NPIX  6000

typedef __attribute__((ext_vector_type(4))) float f32x4;
typedef __attribute__((ext_vector_type(8))) short bf16x8;

__device__ __forceinline__ unsigned short f2bf(float x) {
  __hip_bfloat16 b = __float2bfloat16(x);
  return *reinterpret_cast<unsigned short*>(&b);
}
__device__ __forceinline__ float bf2f(unsigned short u) {
  return __uint_as_float(((unsigned)u) << 16);
}
__device__ __forceinline__ float bf16lo(unsigned int u) {
  return __uint_as_float(u << 16);
}
__device__ __forceinline__ float bf16hi(unsigned int u) {
  return __uint_as_float(u & 0xffff0000u);
}

// ---------------------------------------------------------------------------
// Prep: decompose query into bf16 hi/lo, and transpose+decompose the three
// weight matrices (Wt[n][k] layout for direct MFMA B-fragment loads).
// grid = N_Q + 256 + 128 + 256 blocks, 256 threads.
// ---------------------------------------------------------------------------
__global__ __launch_bounds__(256) void prep_k(
    const float* __restrict__ q,
    const float* __restrict__ oW, const float* __restrict__ wW,
    const float* __restrict__ outW,
    unsigned short* __restrict__ qh,    unsigned short* __restrict__ ql,
    unsigned short* __restrict__ oWth,  unsigned short* __restrict__ oWtl,
    unsigned short* __restrict__ wWth,  unsigned short* __restrict__ wWtl,
    unsigned short* __restrict__ outWth,unsigned short* __restrict__ outWtl) {
  const int b = blockIdx.x, k = threadIdx.x;
  float v; unsigned short *dh, *dl; int idx;
  if (b < N_Q) {
    v = q[b * 256 + k]; dh = qh; dl = ql; idx = b * 256 + k;
  } else if (b < N_Q + 256) {
    int n = b - N_Q; v = oW[k * 256 + n]; dh = oWth; dl = oWtl; idx = n * 256 + k;
  } else if (b < N_Q + 384) {
    int n = b - N_Q - 256; v = wW[k * 128 + n]; dh = wWth; dl = wWtl; idx = n * 256 + k;
  } else {
    int n = b - N_Q - 384; v = outW[k * 256 + n]; dh = outWth; dl = outWtl; idx = n * 256 + k;
  }
  unsigned short hv = f2bf(v);
  dh[idx] = hv;
  dl[idx] = f2bf(v - bf2f(hv));
}

// ---------------------------------------------------------------------------
// Tiled transpose+convert: (6,256,60,100) f32 -> (6,6000,256) bf16 NHWC.
// Block: one cam x 64 pixels; LDS 64x64 f32 tile (+1 pad), 4 channel chunks.
// ---------------------------------------------------------------------------
__global__ __launch_bounds__(256) void transpose_feats_k(
    const float* __restrict__ in, unsigned short* __restrict__ out) {
  __shared__ float tile[64][65];
  const int cam = blockIdx.x / 94;
  const int px0 = (blockIdx.x % 94) * 64;
  const int tid = threadIdx.x;
  const int lpx = tid & 63;
  const int cg  = tid >> 6;
  const int px  = px0 + lpx;
  const bool pv = px < NPIX;

  for (int c0 = 0; c0 < 256; c0 += 64) {
#pragma unroll
    for (int i = 0; i < 16; ++i) {
      int cc = cg * 16 + i;
      tile[lpx][cc] = pv ? in[(cam * 256 + c0 + cc) * NPIX + px] : 0.f;
    }
    __syncthreads();
    const int wc = tid & 63;
    const int pg = tid >> 6;
#pragma unroll
    for (int i = 0; i < 16; ++i) {
      int lp = pg * 16 + i;
      int gpx = px0 + lp;
      if (gpx < NPIX)
        out[(size_t)(cam * NPIX + gpx) * 256 + c0 + wc] = f2bf(tile[lp][wc]);
    }
    __syncthreads();
  }
}

// ---------------------------------------------------------------------------
// MFMA GEMM with bf16 hi/lo split (~fp32 accuracy): C = A @ Bt^T + bias.
// A: [M][256] bf16 hi/lo row-major. Bt: [N][256] bf16 hi/lo (W transposed).
// No LDS: A/B fragments are direct 16B global loads (L2-hot).
// Block 256 thr = 4 waves (2x2), tile 64x64, wave = 32x32 (2x2 frags 16x16).
// mode 1: tanh(v)*0.12 epilogue.
// ---------------------------------------------------------------------------
__global__ __launch_bounds__(256) void gemm_mfma(
    const unsigned short* __restrict__ Ah, const unsigned short* __restrict__ Al,
    const unsigned short* __restrict__ Bh, const unsigned short* __restrict__ Bl,
    const float* __restrict__ bias, float* __restrict__ C,
    int M, int N, int mode) {
  const int tid = threadIdx.x;
  const int l = tid & 63, w = tid >> 6;
  const int wm = w >> 1, wn = w & 1;
  const int bm = blockIdx.x * 64, bn = blockIdx.y * 64;
  const int lr = l & 15;
  const int lk = (l >> 4) * 8;

  const int am0 = min(bm + wm * 32 + lr, M - 1);
  const int am1 = min(bm + wm * 32 + 16 + lr, M - 1);
  const int bn0 = bn + wn * 32 + lr;
  const int bn1 = bn0 + 16;

  const bf16x8* pah0 = (const bf16x8*)(Ah + (size_t)am0 * 256 + lk);
  const bf16x8* pah1 = (const bf16x8*)(Ah + (size_t)am1 * 256 + lk);
  const bf16x8* pal0 = (const bf16x8*)(Al + (size_t)am0 * 256 + lk);
  const bf16x8* pal1 = (const bf16x8*)(Al + (size_t)am1 * 256 + lk);
  const bf16x8* pbh0 = (const bf16x8*)(Bh + (size_t)bn0 * 256 + lk);
  const bf16x8* pbh1 = (const bf16x8*)(Bh + (size_t)bn1 * 256 + lk);
  const bf16x8* pbl0 = (const bf16x8*)(Bl + (size_t)bn0 * 256 + lk);
  const bf16x8* pbl1 = (const bf16x8*)(Bl + (size_t)bn1 * 256 + lk);

  f32x4 acc00 = {}, acc01 = {}, acc10 = {}, acc11 = {};

#pragma unroll 4
  for (int ks = 0; ks < 8; ++ks) {
    bf16x8 ah0 = pah0[ks * 4], ah1 = pah1[ks * 4];
    bf16x8 al0 = pal0[ks * 4], al1 = pal1[ks * 4];
    bf16x8 bh0 = pbh0[ks * 4], bh1 = pbh1[ks * 4];
    bf16x8 bl0 = pbl0[ks * 4], bl1 = pbl1[ks * 4];
    acc00 = __builtin_amdgcn_mfma_f32_16x16x32_bf16(ah0, bh0, acc00, 0, 0, 0);
    acc00 = __builtin_amdgcn_mfma_f32_16x16x32_bf16(ah0, bl0, acc00, 0, 0, 0);
    acc00 = __builtin_amdgcn_mfma_f32_16x16x32_bf16(al0, bh0, acc00, 0, 0, 0);
    acc01 = __builtin_amdgcn_mfma_f32_16x16x32_bf16(ah0, bh1, acc01, 0, 0, 0);
    acc01 = __builtin_amdgcn_mfma_f32_16x16x32_bf16(ah0, bl1, acc01, 0, 0, 0);
    acc01 = __builtin_amdgcn_mfma_f32_16x16x32_bf16(al0, bh1, acc01, 0, 0, 0);
    acc10 = __builtin_amdgcn_mfma_f32_16x16x32_bf16(ah1, bh0, acc10, 0, 0, 0);
    acc10 = __builtin_amdgcn_mfma_f32_16x16x32_bf16(ah1, bl0, acc10, 0, 0, 0);
    acc10 = __builtin_amdgcn_mfma_f32_16x16x32_bf16(al1, bh0, acc10, 0, 0, 0);
    acc11 = __builtin_amdgcn_mfma_f32_16x16x32_bf16(ah1, bh1, acc11, 0, 0, 0);
    acc11 = __builtin_amdgcn_mfma_f32_16x16x32_bf16(ah1, bl1, acc11, 0, 0, 0);
    acc11 = __builtin_amdgcn_mfma_f32_16x16x32_bf16(al1, bh1, acc11, 0, 0, 0);
  }

  // D layout (m89-verified): col = lane&15, row = (lane>>4)*4 + reg
  const float bias0 = bias[bn + wn * 32 + lr];
  const float bias1 = bias[bn + wn * 32 + 16 + lr];
  const int row0 = bm + wm * 32 + (l >> 4) * 4;
  const int col0 = bn + wn * 32 + lr;
#pragma unroll
  for (int r = 0; r < 4; ++r) {
    int rowA = row0 + r, rowB = row0 + 16 + r;
    float v00 = acc00[r] + bias0, v01 = acc01[r] + bias1;
    float v10 = acc10[r] + bias0, v11 = acc11[r] + bias1;
    if (mode == 1) {
      v00 = tanhf(v00) * 0.12f; v01 = tanhf(v01) * 0.12f;
      v10 = tanhf(v10) * 0.12f; v11 = tanhf(v11) * 0.12f;
    }
    if (rowA < M) {
      C[(size_t)rowA * N + col0] = v00;
      C[(size_t)rowA * N + col0 + 16] = v01;
    }
    if (rowB < M) {
      C[(size_t)rowB * N + col0] = v10;
      C[(size_t)rowB * N + col0 + 16] = v11;
    }
  }
}

// ---------------------------------------------------------------------------
// Deformable sampling + masked softmax + cam fusion.
// Block = 2 queries x 128 threads; thread t = (h = t>>4, p = t&15).
// Phase A: thread t computes ITS point's 4 bilinear weights (x softmax w)
//          and 2 packed pixel indices -> 32B in LDS (once, not 16x redundant).
// Phase B: head-group broadcast reads + 16 gather loads per visible pillar.
// Visibility via __ballot bits -> wave-uniform scalar branches; NO barriers
// (phase A->B communication is intra-wave).
// Emits fused directly as bf16 hi/lo for the MFMA out-projection.
// ---------------------------------------------------------------------------
__global__ __launch_bounds__(256) void sample_fuse(
    const unsigned short* __restrict__ ft, // (6,6000,256) bf16
    const float* __restrict__ offs,        // (N,256)
    const float* __restrict__ wlog,        // (N,128)
    const float* __restrict__ refp,        // (6,N,4,2)
    const int*   __restrict__ mask,        // (6,N,4)
    unsigned short* __restrict__ fh,       // (N,256) bf16 hi
    unsigned short* __restrict__ fl) {     // (N,256) bf16 lo
  const int tid = threadIdx.x;
  const int sub = tid >> 7;
  const int t   = tid & 127;
  const int n   = blockIdx.x * 2 + sub;
  const int h   = t >> 4, p = t & 15, pp = p >> 2;

  __shared__ float spt[2][128][8];

  const float2 off = reinterpret_cast<const float2*>(offs)[n * 128 + t];
  const float logit = wlog[n * 128 + t];
  const unsigned int* ftc = reinterpret_cast<const unsigned int*>(ft) + t;

  float acc0 = 0.f, acc1 = 0.f;
  int cnt = 0;

  for (int cam = 0; cam < N_CAM; ++cam) {
    const int vis = mask[(cam * N_Q + n) * 4 + pp];
    const unsigned long long bal = __ballot(vis != 0);
    if (!(bal & 0x1111ULL)) continue;   // no visible pillar for this query/cam
    cnt++;

    // masked softmax over the 16 points of this head (lane-local result)
    float val = vis ? logit : -1e30f;
#pragma unroll
    for (int m = 8; m >= 1; m >>= 1)
      val = fmaxf(val, __shfl_xor(val, m, 16));
    float e = vis ? __expf(logit - val) : 0.f;
    float s = e;
#pragma unroll
    for (int m = 8; m >= 1; m >>= 1)
      s += __shfl_xor(s, m, 16);
    const float wgt = e / fmaxf(s, 1e-6f);

    // Phase A: this thread's point -> weights + packed indices
    const float2 ref = reinterpret_cast<const float2*>(refp)[(cam * N_Q + n) * 4 + pp];
    const float x = fmaf(ref.x + off.x, (float)WIMG, -0.5f);
    const float y = fmaf(ref.y + off.y, (float)HIMG, -0.5f);
    const float x0f = floorf(x), y0f = floorf(y);
    const float wx = x - x0f, wy = y - y0f;
    const int x0 = (int)x0f, y0 = (int)y0f;
    const int x1 = x0 + 1, y1 = y0 + 1;
    const float mx0 = (x0 >= 0 && x0 < WIMG) ? 1.f : 0.f;
    const float mx1 = (x1 >= 0 && x1 < WIMG) ? 1.f : 0.f;
    const float my0 = (y0 >= 0 && y0 < HIMG) ? 1.f : 0.f;
    const float my1 = (y1 >= 0 && y1 < HIMG) ? 1.f : 0.f;
    const int xc0 = min(max(x0, 0), WIMG - 1);
    const int xc1 = min(max(x1, 0), WIMG - 1);
    const int yc0 = min(max(y0, 0), HIMG - 1);
    const int yc1 = min(max(y1, 0), HIMG - 1);
    float* sp = spt[sub][t];
    sp[0] = (1.f - wx) * (1.f - wy) * mx0 * my0 * wgt;
    sp[1] = wx * (1.f - wy) * mx1 * my0 * wgt;
    sp[2] = (1.f - wx) * wy * mx0 * my1 * wgt;
    sp[3] = wx * wy * mx1 * my1 * wgt;
    reinterpret_cast<unsigned int*>(sp)[4] =
        (unsigned)(yc0 * WIMG + xc0) | ((unsigned)(yc0 * WIMG + xc1) << 16);
    reinterpret_cast<unsigned int*>(sp)[5] =
        (unsigned)(yc1 * WIMG + xc0) | ((unsigned)(yc1 * WIMG + xc1) << 16);
    __builtin_amdgcn_wave_barrier();

    // Phase B: gather. Head-group broadcast reads from LDS (conflict-free).
    const unsigned int camb = (unsigned)cam * (NPIX * 128);
#pragma unroll
    for (int pp2 = 0; pp2 < 4; ++pp2) {
      if (!(bal & (1ULL << (pp2 * 4)))) continue;  // wave-uniform
#pragma unroll
      for (int pn = 0; pn < 4; ++pn) {
        const float* spb = spt[sub][h * 16 + pp2 * 4 + pn];
        const f32x4 wv = *reinterpret_cast<const f32x4*>(spb);
        const uint2 pk = *reinterpret_cast<const uint2*>(spb + 4);
        const unsigned int u00 = ftc[camb + (pk.x & 0xffffu) * 128u];
        const unsigned int u10 = ftc[camb + (pk.x >> 16) * 128u];
        const unsigned int u01 = ftc[camb + (pk.y & 0xffffu) * 128u];
        const unsigned int u11 = ftc[camb + (pk.y >> 16) * 128u];
        acc0 = fmaf(bf16lo(u00), wv.x, acc0);
        acc0 = fmaf(bf16lo(u10), wv.y, acc0);
        acc0 = fmaf(bf16lo(u01), wv.z, acc0);
        acc0 = fmaf(bf16lo(u11), wv.w, acc0);
        acc1 = fmaf(bf16hi(u00), wv.x, acc1);
        acc1 = fmaf(bf16hi(u10), wv.y, acc1);
        acc1 = fmaf(bf16hi(u01), wv.z, acc1);
        acc1 = fmaf(bf16hi(u11), wv.w, acc1);
      }
    }
  }

  const float inv = (cnt > 0) ? (1.f / (float)cnt) : 1.f;
  const float v0 = acc0 * inv, v1 = acc1 * inv;
  const unsigned short h0 = f2bf(v0), h1 = f2bf(v1);
  const unsigned short l0 = f2bf(v0 - bf2f(h0)), l1 = f2bf(v1 - bf2f(h1));
  reinterpret_cast<unsigned int*>(fh)[n * 128 + t] = (unsigned)h0 | ((unsigned)h1 << 16);
  reinterpret_cast<unsigned int*>(fl)[n * 128 + t] = (unsigned)l0 | ((unsigned)l1 << 16);
}

// ---------------------------------------------------------------------------
extern "C" void kernel_launch(void* const* d_in, const int* in_sizes, int n_in,
                              void* d_out, int out_size, void* d_ws, size_t ws_size,
                              hipStream_t stream) {
  const float* query = (const float*)d_in[0];
  const float* feats = (const float*)d_in[1];
  const float* refp  = (const float*)d_in[2];
  const int*   mask  = (const int*)d_in[3];
  const float* oW    = (const float*)d_in[4];
  const float* ob    = (const float*)d_in[5];
  const float* wW    = (const float*)d_in[6];
  const float* wb    = (const float*)d_in[7];
  const float* outW  = (const float*)d_in[8];
  const float* outb  = (const float*)d_in[9];
  float* out = (float*)d_out;

  char* wsb = (char*)d_ws;
  size_t o = 0;
  unsigned short* ft = (unsigned short*)(wsb + o); o += (size_t)N_CAM * NPIX * 256 * 2;      // 18.43 MB
  unsigned short* qh = (unsigned short*)(wsb + o); o += (size_t)N_Q * 256 * 2;               // 5.12 MB
  unsigned short* ql = (unsigned short*)(wsb + o); o += (size_t)N_Q * 256 * 2;
  unsigned short* fh = (unsigned short*)(wsb + o); o += (size_t)N_Q * 256 * 2;
  unsigned short* fl = (unsigned short*)(wsb + o); o += (size_t)N_Q * 256 * 2;
  unsigned short* oWth  = (unsigned short*)(wsb + o); o += 256 * 256 * 2;
  unsigned short* oWtl  = (unsigned short*)(wsb + o); o += 256 * 256 * 2;
  unsigned short* wWth  = (unsigned short*)(wsb + o); o += 128 * 256 * 2;
  unsigned short* wWtl  = (unsigned short*)(wsb + o); o += 128 * 256 * 2;
  unsigned short* outWth = (unsigned short*)(wsb + o); o += 256 * 256 * 2;
  unsigned short* outWtl = (unsigned short*)(wsb + o); o += 256 * 256 * 2;
  float* offs = (float*)(wsb + o); o += (size_t)N_Q * 256 * 4;                               // 10.24 MB
  float* wlog = (float*)(wsb + o); o += (size_t)N_Q * 128 * 4;                               // 5.12 MB

  prep_k<<<N_Q + 640, 256, 0, stream>>>(query, oW, wW, outW, qh, ql,
                                        oWth, oWtl, wWth, wWtl, outWth, outWtl);
  transpose_feats_k<<<N_CAM * 94, 256, 0, stream>>>(feats, ft);

  dim3 g1((N_Q + 63) / 64, 4);
  gemm_mfma<<<g1, 256, 0, stream>>>(qh, ql, oWth, oWtl, ob, offs, N_Q, 256, 1);
  dim3 g2((N_Q + 63) / 64, 2);
  gemm_mfma<<<g2, 256, 0, stream>>>(qh, ql, wWth, wWtl, wb, wlog, N_Q, 128, 0);

  sample_fuse<<<N_Q / 2, 256, 0, stream>>>(ft, offs, wlog, refp, mask, fh, fl);

  dim3 g3((N_Q + 63) / 64, 4);
  gemm_mfma<<<g3, 256, 0, stream>>>(fh, fl, outWth, outWtl, outb, out, N_Q, 256, 0);
}

// Round 4
// 217.905 us; speedup vs baseline: 2.4315x; 1.0641x over previous
//
#include <hip/hip_runtime.h>
#include <hip/hip_bf16.h>

#define N_Q   10000
#define N_CAM 6
#define HIMG  60
#define WIMG  100
#define NPIX  6000

typedef __attribute__((ext_vector_type(4))) float f32x4;
typedef __attribute__((ext_vector_type(8))) short bf16x8;

__device__ __forceinline__ unsigned short f2bf(float x) {
  __hip_bfloat16 b = __float2bfloat16(x);
  return *reinterpret_cast<unsigned short*>(&b);
}
__device__ __forceinline__ float bf2f(unsigned short u) {
  return __uint_as_float(((unsigned)u) << 16);
}
__device__ __forceinline__ float bf16lo(unsigned int u) {
  return __uint_as_float(u << 16);
}
__device__ __forceinline__ float bf16hi(unsigned int u) {
  return __uint_as_float(u & 0xffff0000u);
}

// ---------------------------------------------------------------------------
// Prep: decompose query into bf16 hi/lo, transpose+decompose weight matrices.
// ---------------------------------------------------------------------------
__global__ __launch_bounds__(256) void prep_k(
    const float* __restrict__ q,
    const float* __restrict__ oW, const float* __restrict__ wW,
    const float* __restrict__ outW,
    unsigned short* __restrict__ qh,    unsigned short* __restrict__ ql,
    unsigned short* __restrict__ oWth,  unsigned short* __restrict__ oWtl,
    unsigned short* __restrict__ wWth,  unsigned short* __restrict__ wWtl,
    unsigned short* __restrict__ outWth,unsigned short* __restrict__ outWtl) {
  const int b = blockIdx.x, k = threadIdx.x;
  float v; unsigned short *dh, *dl; int idx;
  if (b < N_Q) {
    v = q[b * 256 + k]; dh = qh; dl = ql; idx = b * 256 + k;
  } else if (b < N_Q + 256) {
    int n = b - N_Q; v = oW[k * 256 + n]; dh = oWth; dl = oWtl; idx = n * 256 + k;
  } else if (b < N_Q + 384) {
    int n = b - N_Q - 256; v = wW[k * 128 + n]; dh = wWth; dl = wWtl; idx = n * 256 + k;
  } else {
    int n = b - N_Q - 384; v = outW[k * 256 + n]; dh = outWth; dl = outWtl; idx = n * 256 + k;
  }
  unsigned short hv = f2bf(v);
  dh[idx] = hv;
  dl[idx] = f2bf(v - bf2f(hv));
}

// ---------------------------------------------------------------------------
// Tiled transpose+convert: (6,256,60,100) f32 -> (6,6000,256) bf16 NHWC.
// ---------------------------------------------------------------------------
__global__ __launch_bounds__(256) void transpose_feats_k(
    const float* __restrict__ in, unsigned short* __restrict__ out) {
  __shared__ float tile[64][65];
  const int cam = blockIdx.x / 94;
  const int px0 = (blockIdx.x % 94) * 64;
  const int tid = threadIdx.x;
  const int lpx = tid & 63;
  const int cg  = tid >> 6;
  const int px  = px0 + lpx;
  const bool pv = px < NPIX;

  for (int c0 = 0; c0 < 256; c0 += 64) {
#pragma unroll
    for (int i = 0; i < 16; ++i) {
      int cc = cg * 16 + i;
      tile[lpx][cc] = pv ? in[(cam * 256 + c0 + cc) * NPIX + px] : 0.f;
    }
    __syncthreads();
    const int wc = tid & 63;
    const int pg = tid >> 6;
#pragma unroll
    for (int i = 0; i < 16; ++i) {
      int lp = pg * 16 + i;
      int gpx = px0 + lp;
      if (gpx < NPIX)
        out[(size_t)(cam * NPIX + gpx) * 256 + c0 + wc] = f2bf(tile[lp][wc]);
    }
    __syncthreads();
  }
}

// ---------------------------------------------------------------------------
// MFMA GEMM body: bf16 hi/lo split, C = A @ Bt^T + bias. No LDS.
// Block 256 thr = 4 waves (2x2), tile 64x64, wave 32x32 (2x2 frags 16x16).
// ---------------------------------------------------------------------------
__device__ __forceinline__ void gemm_body(
    const unsigned short* __restrict__ Ah, const unsigned short* __restrict__ Al,
    const unsigned short* __restrict__ Bh, const unsigned short* __restrict__ Bl,
    const float* __restrict__ bias, float* __restrict__ C,
    int M, int N, int mode, int bm, int bn, int tid) {
  const int l = tid & 63, w = tid >> 6;
  const int wm = w >> 1, wn = w & 1;
  const int lr = l & 15;
  const int lk = (l >> 4) * 8;

  const int am0 = min(bm + wm * 32 + lr, M - 1);
  const int am1 = min(bm + wm * 32 + 16 + lr, M - 1);
  const int bn0 = bn + wn * 32 + lr;
  const int bn1 = bn0 + 16;

  const bf16x8* pah0 = (const bf16x8*)(Ah + (size_t)am0 * 256 + lk);
  const bf16x8* pah1 = (const bf16x8*)(Ah + (size_t)am1 * 256 + lk);
  const bf16x8* pal0 = (const bf16x8*)(Al + (size_t)am0 * 256 + lk);
  const bf16x8* pal1 = (const bf16x8*)(Al + (size_t)am1 * 256 + lk);
  const bf16x8* pbh0 = (const bf16x8*)(Bh + (size_t)bn0 * 256 + lk);
  const bf16x8* pbh1 = (const bf16x8*)(Bh + (size_t)bn1 * 256 + lk);
  const bf16x8* pbl0 = (const bf16x8*)(Bl + (size_t)bn0 * 256 + lk);
  const bf16x8* pbl1 = (const bf16x8*)(Bl + (size_t)bn1 * 256 + lk);

  f32x4 acc00 = {}, acc01 = {}, acc10 = {}, acc11 = {};

#pragma unroll 4
  for (int ks = 0; ks < 8; ++ks) {
    bf16x8 ah0 = pah0[ks * 4], ah1 = pah1[ks * 4];
    bf16x8 al0 = pal0[ks * 4], al1 = pal1[ks * 4];
    bf16x8 bh0 = pbh0[ks * 4], bh1 = pbh1[ks * 4];
    bf16x8 bl0 = pbl0[ks * 4], bl1 = pbl1[ks * 4];
    acc00 = __builtin_amdgcn_mfma_f32_16x16x32_bf16(ah0, bh0, acc00, 0, 0, 0);
    acc00 = __builtin_amdgcn_mfma_f32_16x16x32_bf16(ah0, bl0, acc00, 0, 0, 0);
    acc00 = __builtin_amdgcn_mfma_f32_16x16x32_bf16(al0, bh0, acc00, 0, 0, 0);
    acc01 = __builtin_amdgcn_mfma_f32_16x16x32_bf16(ah0, bh1, acc01, 0, 0, 0);
    acc01 = __builtin_amdgcn_mfma_f32_16x16x32_bf16(ah0, bl1, acc01, 0, 0, 0);
    acc01 = __builtin_amdgcn_mfma_f32_16x16x32_bf16(al0, bh1, acc01, 0, 0, 0);
    acc10 = __builtin_amdgcn_mfma_f32_16x16x32_bf16(ah1, bh0, acc10, 0, 0, 0);
    acc10 = __builtin_amdgcn_mfma_f32_16x16x32_bf16(ah1, bl0, acc10, 0, 0, 0);
    acc10 = __builtin_amdgcn_mfma_f32_16x16x32_bf16(al1, bh0, acc10, 0, 0, 0);
    acc11 = __builtin_amdgcn_mfma_f32_16x16x32_bf16(ah1, bh1, acc11, 0, 0, 0);
    acc11 = __builtin_amdgcn_mfma_f32_16x16x32_bf16(ah1, bl1, acc11, 0, 0, 0);
    acc11 = __builtin_amdgcn_mfma_f32_16x16x32_bf16(al1, bh1, acc11, 0, 0, 0);
  }

  const float bias0 = bias[bn + wn * 32 + lr];
  const float bias1 = bias[bn + wn * 32 + 16 + lr];
  const int row0 = bm + wm * 32 + (l >> 4) * 4;
  const int col0 = bn + wn * 32 + lr;
#pragma unroll
  for (int r = 0; r < 4; ++r) {
    int rowA = row0 + r, rowB = row0 + 16 + r;
    float v00 = acc00[r] + bias0, v01 = acc01[r] + bias1;
    float v10 = acc10[r] + bias0, v11 = acc11[r] + bias1;
    if (mode == 1) {
      v00 = tanhf(v00) * 0.12f; v01 = tanhf(v01) * 0.12f;
      v10 = tanhf(v10) * 0.12f; v11 = tanhf(v11) * 0.12f;
    }
    if (rowA < M) {
      C[(size_t)rowA * N + col0] = v00;
      C[(size_t)rowA * N + col0 + 16] = v01;
    }
    if (rowB < M) {
      C[(size_t)rowB * N + col0] = v10;
      C[(size_t)rowB * N + col0 + 16] = v11;
    }
  }
}

// Fused offset+logit GEMMs: blocks_y 0..3 -> offsets (tanh), 4..5 -> logits.
__global__ __launch_bounds__(256) void gemm12_k(
    const unsigned short* __restrict__ Ah, const unsigned short* __restrict__ Al,
    const unsigned short* __restrict__ B1h, const unsigned short* __restrict__ B1l,
    const float* __restrict__ b1, float* __restrict__ C1,
    const unsigned short* __restrict__ B2h, const unsigned short* __restrict__ B2l,
    const float* __restrict__ b2, float* __restrict__ C2) {
  const int by = blockIdx.y;
  if (by < 4)
    gemm_body(Ah, Al, B1h, B1l, b1, C1, N_Q, 256, 1,
              blockIdx.x * 64, by * 64, threadIdx.x);
  else
    gemm_body(Ah, Al, B2h, B2l, b2, C2, N_Q, 128, 0,
              blockIdx.x * 64, (by - 4) * 64, threadIdx.x);
}

__global__ __launch_bounds__(256) void gemm_out_k(
    const unsigned short* __restrict__ Ah, const unsigned short* __restrict__ Al,
    const unsigned short* __restrict__ Bh, const unsigned short* __restrict__ Bl,
    const float* __restrict__ bias, float* __restrict__ C) {
  gemm_body(Ah, Al, Bh, Bl, bias, C, N_Q, 256, 0,
            blockIdx.x * 64, blockIdx.y * 64, threadIdx.x);
}

// ---------------------------------------------------------------------------
// Deformable sampling + masked softmax + cam fusion.
// Block = 2 queries x 128 threads.
// Phase A: thread t=(h, p) computes ITS point's 4 corner weights (x softmax)
//          + 4 pixel indices -> LDS (9-dword point stride, 152-dword head
//          stride -> conflict-free phase-B reads: banks 24h+9p+c).
// Phase B: lane t=(h, corner c=(t>>2)&3, chunk ch=t&3) gathers one uint4
//          (8 channels, 16B) per point -> 4x fewer load instrs, 4x MLP.
// Corner reduction: one shfl_xor butterfly (xor 4, xor 8) at the very end.
// ---------------------------------------------------------------------------
__global__ __launch_bounds__(256) void sample_fuse(
    const unsigned short* __restrict__ ft, // (6,6000,256) bf16
    const float* __restrict__ offs,        // (N,256)
    const float* __restrict__ wlog,        // (N,128)
    const float* __restrict__ refp,        // (6,N,4,2)
    const int*   __restrict__ mask,        // (6,N,4)
    unsigned short* __restrict__ fh,       // (N,256) bf16 hi
    unsigned short* __restrict__ fl) {     // (N,256) bf16 lo
  const int tid = threadIdx.x;
  const int sub = tid >> 7;
  const int t   = tid & 127;
  const int n   = blockIdx.x * 2 + sub;
  const int h   = t >> 4;
  const int p   = t & 15;          // phase-A point
  const int pp  = p >> 2;
  const int c   = (t >> 2) & 3;    // phase-B corner
  const int ch  = t & 3;           // phase-B channel chunk

  __shared__ float spt[2][1216];
  float* lds = spt[sub];
  unsigned int* ldsu = reinterpret_cast<unsigned int*>(lds);

  const float2 off = reinterpret_cast<const float2*>(offs)[n * 128 + t];
  const float logit = wlog[n * 128 + t];
  const uint4* ftq = reinterpret_cast<const uint4*>(ft);

  float acc[8] = {0.f, 0.f, 0.f, 0.f, 0.f, 0.f, 0.f, 0.f};
  int cnt = 0;
  const int abase = h * 152 + p * 9;
  const int rbase = h * 152;
  const unsigned gbase = (unsigned)(h * 4 + ch);

  for (int cam = 0; cam < N_CAM; ++cam) {
    const int vis = mask[(cam * N_Q + n) * 4 + pp];
    const unsigned long long bal = __ballot(vis != 0);
    if (!(bal & 0x1111ULL)) continue;
    cnt++;

    // masked softmax over the 16 points of this head
    float val = vis ? logit : -1e30f;
#pragma unroll
    for (int m = 8; m >= 1; m >>= 1)
      val = fmaxf(val, __shfl_xor(val, m, 16));
    float e = vis ? __expf(logit - val) : 0.f;
    float s = e;
#pragma unroll
    for (int m = 8; m >= 1; m >>= 1)
      s += __shfl_xor(s, m, 16);
    const float wgt = e / fmaxf(s, 1e-6f);

    // Phase A
    const float2 ref = reinterpret_cast<const float2*>(refp)[(cam * N_Q + n) * 4 + pp];
    const float x = fmaf(ref.x + off.x, (float)WIMG, -0.5f);
    const float y = fmaf(ref.y + off.y, (float)HIMG, -0.5f);
    const float x0f = floorf(x), y0f = floorf(y);
    const float wx = x - x0f, wy = y - y0f;
    const int x0 = (int)x0f, y0 = (int)y0f;
    const int x1 = x0 + 1, y1 = y0 + 1;
    const float mx0 = (x0 >= 0 && x0 < WIMG) ? 1.f : 0.f;
    const float mx1 = (x1 >= 0 && x1 < WIMG) ? 1.f : 0.f;
    const float my0 = (y0 >= 0 && y0 < HIMG) ? 1.f : 0.f;
    const float my1 = (y1 >= 0 && y1 < HIMG) ? 1.f : 0.f;
    const int xc0 = min(max(x0, 0), WIMG - 1);
    const int xc1 = min(max(x1, 0), WIMG - 1);
    const int yc0 = min(max(y0, 0), HIMG - 1);
    const int yc1 = min(max(y1, 0), HIMG - 1);
    lds[abase + 0] = (1.f - wx) * (1.f - wy) * mx0 * my0 * wgt;
    lds[abase + 1] = wx * (1.f - wy) * mx1 * my0 * wgt;
    lds[abase + 2] = (1.f - wx) * wy * mx0 * my1 * wgt;
    lds[abase + 3] = wx * wy * mx1 * my1 * wgt;
    ldsu[abase + 4] = (unsigned)(yc0 * WIMG + xc0);
    ldsu[abase + 5] = (unsigned)(yc0 * WIMG + xc1);
    ldsu[abase + 6] = (unsigned)(yc1 * WIMG + xc0);
    ldsu[abase + 7] = (unsigned)(yc1 * WIMG + xc1);
    __builtin_amdgcn_wave_barrier();

    // Phase B: one uint4 gather per point per lane
    const unsigned camq = (unsigned)cam * (NPIX * 32);
#pragma unroll
    for (int pp2 = 0; pp2 < 4; ++pp2) {
      if (!((bal >> (pp2 * 4)) & 1ULL)) continue;  // wave-uniform
#pragma unroll
      for (int pn = 0; pn < 4; ++pn) {
        const int b = rbase + (pp2 * 4 + pn) * 9;
        const float wv = lds[b + c];
        const unsigned pix = ldsu[b + 4 + c];
        const uint4 u = ftq[camq + pix * 32u + gbase];
        acc[0] = fmaf(bf16lo(u.x), wv, acc[0]);
        acc[1] = fmaf(bf16hi(u.x), wv, acc[1]);
        acc[2] = fmaf(bf16lo(u.y), wv, acc[2]);
        acc[3] = fmaf(bf16hi(u.y), wv, acc[3]);
        acc[4] = fmaf(bf16lo(u.z), wv, acc[4]);
        acc[5] = fmaf(bf16hi(u.z), wv, acc[5]);
        acc[6] = fmaf(bf16lo(u.w), wv, acc[6]);
        acc[7] = fmaf(bf16hi(u.w), wv, acc[7]);
      }
    }
    __builtin_amdgcn_wave_barrier();   // before next cam overwrites LDS
  }

  const float inv = (cnt > 0) ? (1.f / (float)cnt) : 1.f;
#pragma unroll
  for (int j = 0; j < 8; ++j) acc[j] *= inv;
  // reduce over the 4 corner lanes (bits 2-3 of lane id)
#pragma unroll
  for (int j = 0; j < 8; ++j) acc[j] += __shfl_xor(acc[j], 4);
#pragma unroll
  for (int j = 0; j < 8; ++j) acc[j] += __shfl_xor(acc[j], 8);

  if (c == 0) {
    unsigned hw[4], lw[4];
#pragma unroll
    for (int j = 0; j < 4; ++j) {
      const float v0 = acc[2 * j], v1 = acc[2 * j + 1];
      const unsigned short h0 = f2bf(v0), h1 = f2bf(v1);
      const unsigned short l0 = f2bf(v0 - bf2f(h0)), l1 = f2bf(v1 - bf2f(h1));
      hw[j] = (unsigned)h0 | ((unsigned)h1 << 16);
      lw[j] = (unsigned)l0 | ((unsigned)l1 << 16);
    }
    uint4 vh, vl;
    vh.x = hw[0]; vh.y = hw[1]; vh.z = hw[2]; vh.w = hw[3];
    vl.x = lw[0]; vl.y = lw[1]; vl.z = lw[2]; vl.w = lw[3];
    const int widx = n * 32 + h * 4 + ch;
    reinterpret_cast<uint4*>(fh)[widx] = vh;
    reinterpret_cast<uint4*>(fl)[widx] = vl;
  }
}

// ---------------------------------------------------------------------------
extern "C" void kernel_launch(void* const* d_in, const int* in_sizes, int n_in,
                              void* d_out, int out_size, void* d_ws, size_t ws_size,
                              hipStream_t stream) {
  const float* query = (const float*)d_in[0];
  const float* feats = (const float*)d_in[1];
  const float* refp  = (const float*)d_in[2];
  const int*   mask  = (const int*)d_in[3];
  const float* oW    = (const float*)d_in[4];
  const float* ob    = (const float*)d_in[5];
  const float* wW    = (const float*)d_in[6];
  const float* wb    = (const float*)d_in[7];
  const float* outW  = (const float*)d_in[8];
  const float* outb  = (const float*)d_in[9];
  float* out = (float*)d_out;

  char* wsb = (char*)d_ws;
  size_t o = 0;
  unsigned short* ft = (unsigned short*)(wsb + o); o += (size_t)N_CAM * NPIX * 256 * 2;
  unsigned short* qh = (unsigned short*)(wsb + o); o += (size_t)N_Q * 256 * 2;
  unsigned short* ql = (unsigned short*)(wsb + o); o += (size_t)N_Q * 256 * 2;
  unsigned short* fh = (unsigned short*)(wsb + o); o += (size_t)N_Q * 256 * 2;
  unsigned short* fl = (unsigned short*)(wsb + o); o += (size_t)N_Q * 256 * 2;
  unsigned short* oWth  = (unsigned short*)(wsb + o); o += 256 * 256 * 2;
  unsigned short* oWtl  = (unsigned short*)(wsb + o); o += 256 * 256 * 2;
  unsigned short* wWth  = (unsigned short*)(wsb + o); o += 128 * 256 * 2;
  unsigned short* wWtl  = (unsigned short*)(wsb + o); o += 128 * 256 * 2;
  unsigned short* outWth = (unsigned short*)(wsb + o); o += 256 * 256 * 2;
  unsigned short* outWtl = (unsigned short*)(wsb + o); o += 256 * 256 * 2;
  float* offs = (float*)(wsb + o); o += (size_t)N_Q * 256 * 4;
  float* wlog = (float*)(wsb + o); o += (size_t)N_Q * 128 * 4;

  prep_k<<<N_Q + 640, 256, 0, stream>>>(query, oW, wW, outW, qh, ql,
                                        oWth, oWtl, wWth, wWtl, outWth, outWtl);
  transpose_feats_k<<<N_CAM * 94, 256, 0, stream>>>(feats, ft);

  dim3 g12((N_Q + 63) / 64, 6);
  gemm12_k<<<g12, 256, 0, stream>>>(qh, ql, oWth, oWtl, ob, offs,
                                    wWth, wWtl, wb, wlog);

  sample_fuse<<<N_Q / 2, 256, 0, stream>>>(ft, offs, wlog, refp, mask, fh, fl);

  dim3 g3((N_Q + 63) / 64, 4);
  gemm_out_k<<<g3, 256, 0, stream>>>(fh, fl, outWth, outWtl, outb, out);
}

// Round 5
// 209.829 us; speedup vs baseline: 2.5250x; 1.0385x over previous
//
#include <hip/hip_runtime.h>
#include <hip/hip_bf16.h>

#define N_Q   10000
#define N_CAM 6
#define HIMG  60
#define WIMG  100
#define NPIX  6000

typedef __attribute__((ext_vector_type(4))) float f32x4;
typedef __attribute__((ext_vector_type(8))) short bf16x8;

__device__ __forceinline__ unsigned short f2bf(float x) {
  __hip_bfloat16 b = __float2bfloat16(x);
  return *reinterpret_cast<unsigned short*>(&b);
}
__device__ __forceinline__ float bf2f(unsigned short u) {
  return __uint_as_float(((unsigned)u) << 16);
}
__device__ __forceinline__ float bf16lo(unsigned int u) {
  return __uint_as_float(u << 16);
}
__device__ __forceinline__ float bf16hi(unsigned int u) {
  return __uint_as_float(u & 0xffff0000u);
}

// ---------------------------------------------------------------------------
// Merged prep: blocks [0,564) transpose feats (6,256,60,100)f32->(6,6000,256)
// bf16 NHWC; blocks [564, ...) decompose query + transposed weights to hi/lo.
// ---------------------------------------------------------------------------
#define TRANS_BLKS (N_CAM * 94)

__global__ __launch_bounds__(256) void prep_trans_k(
    const float* __restrict__ in,   // image feats
    const float* __restrict__ q,
    const float* __restrict__ oW, const float* __restrict__ wW,
    const float* __restrict__ outW,
    unsigned short* __restrict__ ftout,
    unsigned short* __restrict__ qh,    unsigned short* __restrict__ ql,
    unsigned short* __restrict__ oWth,  unsigned short* __restrict__ oWtl,
    unsigned short* __restrict__ wWth,  unsigned short* __restrict__ wWtl,
    unsigned short* __restrict__ outWth,unsigned short* __restrict__ outWtl) {
  __shared__ float tile[64][65];
  const int tid = threadIdx.x;
  if (blockIdx.x < TRANS_BLKS) {
    const int cam = blockIdx.x / 94;
    const int px0 = (blockIdx.x % 94) * 64;
    const int lpx = tid & 63;
    const int cg  = tid >> 6;
    const int px  = px0 + lpx;
    const bool pv = px < NPIX;

    for (int c0 = 0; c0 < 256; c0 += 64) {
#pragma unroll
      for (int i = 0; i < 16; ++i) {
        int cc = cg * 16 + i;
        tile[lpx][cc] = pv ? in[(cam * 256 + c0 + cc) * NPIX + px] : 0.f;
      }
      __syncthreads();
      const int wc = tid & 63;
      const int pg = tid >> 6;
#pragma unroll
      for (int i = 0; i < 16; ++i) {
        int lp = pg * 16 + i;
        int gpx = px0 + lp;
        if (gpx < NPIX)
          ftout[(size_t)(cam * NPIX + gpx) * 256 + c0 + wc] = f2bf(tile[lp][wc]);
      }
      __syncthreads();
    }
    return;
  }
  const int b = blockIdx.x - TRANS_BLKS;
  const int k = tid;
  float v; unsigned short *dh, *dl; int idx;
  if (b < N_Q) {
    v = q[b * 256 + k]; dh = qh; dl = ql; idx = b * 256 + k;
  } else if (b < N_Q + 256) {
    int nn = b - N_Q; v = oW[k * 256 + nn]; dh = oWth; dl = oWtl; idx = nn * 256 + k;
  } else if (b < N_Q + 384) {
    int nn = b - N_Q - 256; v = wW[k * 128 + nn]; dh = wWth; dl = wWtl; idx = nn * 256 + k;
  } else {
    int nn = b - N_Q - 384; v = outW[k * 256 + nn]; dh = outWth; dl = outWtl; idx = nn * 256 + k;
  }
  unsigned short hv = f2bf(v);
  dh[idx] = hv;
  dl[idx] = f2bf(v - bf2f(hv));
}

// ---------------------------------------------------------------------------
// MFMA GEMM body: bf16 hi/lo split, C = A @ Bt^T + bias. No LDS, full unroll.
// Block 256 thr = 4 waves (2x2), tile 64x64, wave 32x32 (2x2 frags 16x16).
// ---------------------------------------------------------------------------
__device__ __forceinline__ void gemm_body(
    const unsigned short* __restrict__ Ah, const unsigned short* __restrict__ Al,
    const unsigned short* __restrict__ Bh, const unsigned short* __restrict__ Bl,
    const float* __restrict__ bias, float* __restrict__ C,
    int M, int N, int mode, int bm, int bn, int tid) {
  const int l = tid & 63, w = tid >> 6;
  const int wm = w >> 1, wn = w & 1;
  const int lr = l & 15;
  const int lk = (l >> 4) * 8;

  const int am0 = min(bm + wm * 32 + lr, M - 1);
  const int am1 = min(bm + wm * 32 + 16 + lr, M - 1);
  const int bn0 = bn + wn * 32 + lr;
  const int bn1 = bn0 + 16;

  const bf16x8* pah0 = (const bf16x8*)(Ah + (size_t)am0 * 256 + lk);
  const bf16x8* pah1 = (const bf16x8*)(Ah + (size_t)am1 * 256 + lk);
  const bf16x8* pal0 = (const bf16x8*)(Al + (size_t)am0 * 256 + lk);
  const bf16x8* pal1 = (const bf16x8*)(Al + (size_t)am1 * 256 + lk);
  const bf16x8* pbh0 = (const bf16x8*)(Bh + (size_t)bn0 * 256 + lk);
  const bf16x8* pbh1 = (const bf16x8*)(Bh + (size_t)bn1 * 256 + lk);
  const bf16x8* pbl0 = (const bf16x8*)(Bl + (size_t)bn0 * 256 + lk);
  const bf16x8* pbl1 = (const bf16x8*)(Bl + (size_t)bn1 * 256 + lk);

  f32x4 acc00 = {}, acc01 = {}, acc10 = {}, acc11 = {};

#pragma unroll
  for (int ks = 0; ks < 8; ++ks) {
    bf16x8 ah0 = pah0[ks * 4], ah1 = pah1[ks * 4];
    bf16x8 al0 = pal0[ks * 4], al1 = pal1[ks * 4];
    bf16x8 bh0 = pbh0[ks * 4], bh1 = pbh1[ks * 4];
    bf16x8 bl0 = pbl0[ks * 4], bl1 = pbl1[ks * 4];
    acc00 = __builtin_amdgcn_mfma_f32_16x16x32_bf16(ah0, bh0, acc00, 0, 0, 0);
    acc00 = __builtin_amdgcn_mfma_f32_16x16x32_bf16(ah0, bl0, acc00, 0, 0, 0);
    acc00 = __builtin_amdgcn_mfma_f32_16x16x32_bf16(al0, bh0, acc00, 0, 0, 0);
    acc01 = __builtin_amdgcn_mfma_f32_16x16x32_bf16(ah0, bh1, acc01, 0, 0, 0);
    acc01 = __builtin_amdgcn_mfma_f32_16x16x32_bf16(ah0, bl1, acc01, 0, 0, 0);
    acc01 = __builtin_amdgcn_mfma_f32_16x16x32_bf16(al0, bh1, acc01, 0, 0, 0);
    acc10 = __builtin_amdgcn_mfma_f32_16x16x32_bf16(ah1, bh0, acc10, 0, 0, 0);
    acc10 = __builtin_amdgcn_mfma_f32_16x16x32_bf16(ah1, bl0, acc10, 0, 0, 0);
    acc10 = __builtin_amdgcn_mfma_f32_16x16x32_bf16(al1, bh0, acc10, 0, 0, 0);
    acc11 = __builtin_amdgcn_mfma_f32_16x16x32_bf16(ah1, bh1, acc11, 0, 0, 0);
    acc11 = __builtin_amdgcn_mfma_f32_16x16x32_bf16(ah1, bl1, acc11, 0, 0, 0);
    acc11 = __builtin_amdgcn_mfma_f32_16x16x32_bf16(al1, bh1, acc11, 0, 0, 0);
  }

  const float bias0 = bias[bn + wn * 32 + lr];
  const float bias1 = bias[bn + wn * 32 + 16 + lr];
  const int row0 = bm + wm * 32 + (l >> 4) * 4;
  const int col0 = bn + wn * 32 + lr;
#pragma unroll
  for (int r = 0; r < 4; ++r) {
    int rowA = row0 + r, rowB = row0 + 16 + r;
    float v00 = acc00[r] + bias0, v01 = acc01[r] + bias1;
    float v10 = acc10[r] + bias0, v11 = acc11[r] + bias1;
    if (mode == 1) {
      v00 = tanhf(v00) * 0.12f; v01 = tanhf(v01) * 0.12f;
      v10 = tanhf(v10) * 0.12f; v11 = tanhf(v11) * 0.12f;
    }
    if (rowA < M) {
      C[(size_t)rowA * N + col0] = v00;
      C[(size_t)rowA * N + col0 + 16] = v01;
    }
    if (rowB < M) {
      C[(size_t)rowB * N + col0] = v10;
      C[(size_t)rowB * N + col0 + 16] = v11;
    }
  }
}

// Fused offset+logit GEMMs: blocks_y 0..3 -> offsets (tanh), 4..5 -> logits.
__global__ __launch_bounds__(256) void gemm12_k(
    const unsigned short* __restrict__ Ah, const unsigned short* __restrict__ Al,
    const unsigned short* __restrict__ B1h, const unsigned short* __restrict__ B1l,
    const float* __restrict__ b1, float* __restrict__ C1,
    const unsigned short* __restrict__ B2h, const unsigned short* __restrict__ B2l,
    const float* __restrict__ b2, float* __restrict__ C2) {
  const int by = blockIdx.y;
  if (by < 4)
    gemm_body(Ah, Al, B1h, B1l, b1, C1, N_Q, 256, 1,
              blockIdx.x * 64, by * 64, threadIdx.x);
  else
    gemm_body(Ah, Al, B2h, B2l, b2, C2, N_Q, 128, 0,
              blockIdx.x * 64, (by - 4) * 64, threadIdx.x);
}

__global__ __launch_bounds__(256) void gemm_out_k(
    const unsigned short* __restrict__ Ah, const unsigned short* __restrict__ Al,
    const unsigned short* __restrict__ Bh, const unsigned short* __restrict__ Bl,
    const float* __restrict__ bias, float* __restrict__ C) {
  gemm_body(Ah, Al, Bh, Bl, bias, C, N_Q, 256, 0,
            blockIdx.x * 64, blockIdx.y * 64, threadIdx.x);
}

// ---------------------------------------------------------------------------
// Deformable sampling + masked softmax + cam fusion.
// Block = 2 queries x 128 threads.
// Phase A: thread t=(h, p) computes ITS point's 4 corner weights (x softmax)
//          + 4 pixel indices -> LDS (9-dword stride, conflict-free reads).
// Phase B: lane t=(h, corner c, chunk ch) issues ALL visible pillars' uint4
//          gathers (up to 16 = 256B/lane in flight) BEFORE consuming any ->
//          4x memory-level parallelism vs per-pillar issue/consume.
// Corner reduction: shfl_xor butterfly (xor 4, xor 8) at the very end.
// ---------------------------------------------------------------------------
__global__ __launch_bounds__(256) void sample_fuse(
    const unsigned short* __restrict__ ft, // (6,6000,256) bf16
    const float* __restrict__ offs,        // (N,256)
    const float* __restrict__ wlog,        // (N,128)
    const float* __restrict__ refp,        // (6,N,4,2)
    const int*   __restrict__ mask,        // (6,N,4)
    unsigned short* __restrict__ fh,       // (N,256) bf16 hi
    unsigned short* __restrict__ fl) {     // (N,256) bf16 lo
  const int tid = threadIdx.x;
  const int sub = tid >> 7;
  const int t   = tid & 127;
  const int n   = blockIdx.x * 2 + sub;
  const int h   = t >> 4;
  const int p   = t & 15;          // phase-A point
  const int pp  = p >> 2;
  const int c   = (t >> 2) & 3;    // phase-B corner
  const int ch  = t & 3;           // phase-B channel chunk

  __shared__ float spt[2][1216];
  float* lds = spt[sub];
  unsigned int* ldsu = reinterpret_cast<unsigned int*>(lds);

  const float2 off = reinterpret_cast<const float2*>(offs)[n * 128 + t];
  const float logit = wlog[n * 128 + t];
  const uint4* ftq = reinterpret_cast<const uint4*>(ft);

  float acc[8] = {0.f, 0.f, 0.f, 0.f, 0.f, 0.f, 0.f, 0.f};
  int cnt = 0;
  const int abase = h * 152 + p * 9;
  const int rbase = h * 152;
  const unsigned gbase = (unsigned)(h * 4 + ch);

  for (int cam = 0; cam < N_CAM; ++cam) {
    const int vis = mask[(cam * N_Q + n) * 4 + pp];
    const unsigned long long bal = __ballot(vis != 0);
    if (!(bal & 0x1111ULL)) continue;
    cnt++;

    // masked softmax over the 16 points of this head
    float val = vis ? logit : -1e30f;
#pragma unroll
    for (int m = 8; m >= 1; m >>= 1)
      val = fmaxf(val, __shfl_xor(val, m, 16));
    float e = vis ? __expf(logit - val) : 0.f;
    float s = e;
#pragma unroll
    for (int m = 8; m >= 1; m >>= 1)
      s += __shfl_xor(s, m, 16);
    const float wgt = e / fmaxf(s, 1e-6f);

    // Phase A
    const float2 ref = reinterpret_cast<const float2*>(refp)[(cam * N_Q + n) * 4 + pp];
    const float x = fmaf(ref.x + off.x, (float)WIMG, -0.5f);
    const float y = fmaf(ref.y + off.y, (float)HIMG, -0.5f);
    const float x0f = floorf(x), y0f = floorf(y);
    const float wx = x - x0f, wy = y - y0f;
    const int x0 = (int)x0f, y0 = (int)y0f;
    const int x1 = x0 + 1, y1 = y0 + 1;
    const float mx0 = (x0 >= 0 && x0 < WIMG) ? 1.f : 0.f;
    const float mx1 = (x1 >= 0 && x1 < WIMG) ? 1.f : 0.f;
    const float my0 = (y0 >= 0 && y0 < HIMG) ? 1.f : 0.f;
    const float my1 = (y1 >= 0 && y1 < HIMG) ? 1.f : 0.f;
    const int xc0 = min(max(x0, 0), WIMG - 1);
    const int xc1 = min(max(x1, 0), WIMG - 1);
    const int yc0 = min(max(y0, 0), HIMG - 1);
    const int yc1 = min(max(y1, 0), HIMG - 1);
    lds[abase + 0] = (1.f - wx) * (1.f - wy) * mx0 * my0 * wgt;
    lds[abase + 1] = wx * (1.f - wy) * mx1 * my0 * wgt;
    lds[abase + 2] = (1.f - wx) * wy * mx0 * my1 * wgt;
    lds[abase + 3] = wx * wy * mx1 * my1 * wgt;
    ldsu[abase + 4] = (unsigned)(yc0 * WIMG + xc0);
    ldsu[abase + 5] = (unsigned)(yc0 * WIMG + xc1);
    ldsu[abase + 6] = (unsigned)(yc1 * WIMG + xc0);
    ldsu[abase + 7] = (unsigned)(yc1 * WIMG + xc1);
    __builtin_amdgcn_wave_barrier();

    // Phase B: issue ALL visible pillars' gathers, then consume.
    const unsigned camq = (unsigned)cam * (NPIX * 32);
    const bool pv0 = (bal      ) & 1ULL;
    const bool pv1 = (bal >>  4) & 1ULL;
    const bool pv2 = (bal >>  8) & 1ULL;
    const bool pv3 = (bal >> 12) & 1ULL;
    uint4 u0[4], u1[4], u2[4], u3[4];

#define ISSUE(U, P)                                                          \
    if (pv##P) {                                                             \
      _Pragma("unroll")                                                      \
      for (int pn = 0; pn < 4; ++pn) {                                       \
        const unsigned pix = ldsu[rbase + ((P) * 4 + pn) * 9 + 4 + c];       \
        U[pn] = ftq[camq + pix * 32u + gbase];                               \
      }                                                                      \
    }
    ISSUE(u0, 0) ISSUE(u1, 1) ISSUE(u2, 2) ISSUE(u3, 3)

#define CONSUME(U, P)                                                        \
    if (pv##P) {                                                             \
      _Pragma("unroll")                                                      \
      for (int pn = 0; pn < 4; ++pn) {                                       \
        const float wv = lds[rbase + ((P) * 4 + pn) * 9 + c];                \
        acc[0] = fmaf(bf16lo(U[pn].x), wv, acc[0]);                          \
        acc[1] = fmaf(bf16hi(U[pn].x), wv, acc[1]);                          \
        acc[2] = fmaf(bf16lo(U[pn].y), wv, acc[2]);                          \
        acc[3] = fmaf(bf16hi(U[pn].y), wv, acc[3]);                          \
        acc[4] = fmaf(bf16lo(U[pn].z), wv, acc[4]);                          \
        acc[5] = fmaf(bf16hi(U[pn].z), wv, acc[5]);                          \
        acc[6] = fmaf(bf16lo(U[pn].w), wv, acc[6]);                          \
        acc[7] = fmaf(bf16hi(U[pn].w), wv, acc[7]);                          \
      }                                                                      \
    }
    CONSUME(u0, 0) CONSUME(u1, 1) CONSUME(u2, 2) CONSUME(u3, 3)
#undef ISSUE
#undef CONSUME
    __builtin_amdgcn_wave_barrier();   // before next cam overwrites LDS
  }

  const float inv = (cnt > 0) ? (1.f / (float)cnt) : 1.f;
#pragma unroll
  for (int j = 0; j < 8; ++j) acc[j] *= inv;
#pragma unroll
  for (int j = 0; j < 8; ++j) acc[j] += __shfl_xor(acc[j], 4);
#pragma unroll
  for (int j = 0; j < 8; ++j) acc[j] += __shfl_xor(acc[j], 8);

  if (c == 0) {
    unsigned hw[4], lw[4];
#pragma unroll
    for (int j = 0; j < 4; ++j) {
      const float v0 = acc[2 * j], v1 = acc[2 * j + 1];
      const unsigned short h0 = f2bf(v0), h1 = f2bf(v1);
      const unsigned short l0 = f2bf(v0 - bf2f(h0)), l1 = f2bf(v1 - bf2f(h1));
      hw[j] = (unsigned)h0 | ((unsigned)h1 << 16);
      lw[j] = (unsigned)l0 | ((unsigned)l1 << 16);
    }
    uint4 vh, vl;
    vh.x = hw[0]; vh.y = hw[1]; vh.z = hw[2]; vh.w = hw[3];
    vl.x = lw[0]; vl.y = lw[1]; vl.z = lw[2]; vl.w = lw[3];
    const int widx = n * 32 + h * 4 + ch;
    reinterpret_cast<uint4*>(fh)[widx] = vh;
    reinterpret_cast<uint4*>(fl)[widx] = vl;
  }
}

// ---------------------------------------------------------------------------
extern "C" void kernel_launch(void* const* d_in, const int* in_sizes, int n_in,
                              void* d_out, int out_size, void* d_ws, size_t ws_size,
                              hipStream_t stream) {
  const float* query = (const float*)d_in[0];
  const float* feats = (const float*)d_in[1];
  const float* refp  = (const float*)d_in[2];
  const int*   mask  = (const int*)d_in[3];
  const float* oW    = (const float*)d_in[4];
  const float* ob    = (const float*)d_in[5];
  const float* wW    = (const float*)d_in[6];
  const float* wb    = (const float*)d_in[7];
  const float* outW  = (const float*)d_in[8];
  const float* outb  = (const float*)d_in[9];
  float* out = (float*)d_out;

  char* wsb = (char*)d_ws;
  size_t o = 0;
  unsigned short* ft = (unsigned short*)(wsb + o); o += (size_t)N_CAM * NPIX * 256 * 2;
  unsigned short* qh = (unsigned short*)(wsb + o); o += (size_t)N_Q * 256 * 2;
  unsigned short* ql = (unsigned short*)(wsb + o); o += (size_t)N_Q * 256 * 2;
  unsigned short* fh = (unsigned short*)(wsb + o); o += (size_t)N_Q * 256 * 2;
  unsigned short* fl = (unsigned short*)(wsb + o); o += (size_t)N_Q * 256 * 2;
  unsigned short* oWth  = (unsigned short*)(wsb + o); o += 256 * 256 * 2;
  unsigned short* oWtl  = (unsigned short*)(wsb + o); o += 256 * 256 * 2;
  unsigned short* wWth  = (unsigned short*)(wsb + o); o += 128 * 256 * 2;
  unsigned short* wWtl  = (unsigned short*)(wsb + o); o += 128 * 256 * 2;
  unsigned short* outWth = (unsigned short*)(wsb + o); o += 256 * 256 * 2;
  unsigned short* outWtl = (unsigned short*)(wsb + o); o += 256 * 256 * 2;
  float* offs = (float*)(wsb + o); o += (size_t)N_Q * 256 * 4;
  float* wlog = (float*)(wsb + o); o += (size_t)N_Q * 128 * 4;

  prep_trans_k<<<TRANS_BLKS + N_Q + 640, 256, 0, stream>>>(
      feats, query, oW, wW, outW, ft, qh, ql,
      oWth, oWtl, wWth, wWtl, outWth, outWtl);

  dim3 g12((N_Q + 63) / 64, 6);
  gemm12_k<<<g12, 256, 0, stream>>>(qh, ql, oWth, oWtl, ob, offs,
                                    wWth, wWtl, wb, wlog);

  sample_fuse<<<N_Q / 2, 256, 0, stream>>>(ft, offs, wlog, refp, mask, fh, fl);

  dim3 g3((N_Q + 63) / 64, 4);
  gemm_out_k<<<g3, 256, 0, stream>>>(fh, fl, outWth, outWtl, outb, out);
}

// Round 6
// 170.224 us; speedup vs baseline: 3.1126x; 1.2327x over previous
//
#include <hip/hip_runtime.h>
#include <hip/hip_bf16.h>

#define N_Q   10000
#define N_CAM 6
#define HIMG  60
#define WIMG  100
#define NPIX  6000

typedef __attribute__((ext_vector_type(4))) float f32x4;
typedef __attribute__((ext_vector_type(8))) short bf16x8;

__device__ __forceinline__ unsigned short f2bf(float x) {
  __hip_bfloat16 b = __float2bfloat16(x);
  return *reinterpret_cast<unsigned short*>(&b);
}
__device__ __forceinline__ float bf2f(unsigned short u) {
  return __uint_as_float(((unsigned)u) << 16);
}
__device__ __forceinline__ float bf16lo(unsigned int u) {
  return __uint_as_float(u << 16);
}
__device__ __forceinline__ float bf16hi(unsigned int u) {
  return __uint_as_float(u & 0xffff0000u);
}

// ---------------------------------------------------------------------------
// Merged prep: blocks [0,564) transpose feats (6,256,60,100)f32->(6,6000,256)
// bf16 NHWC; blocks [564, ...) decompose query + transposed weights to hi/lo.
// ---------------------------------------------------------------------------
#define TRANS_BLKS (N_CAM * 94)

__global__ __launch_bounds__(256) void prep_trans_k(
    const float* __restrict__ in,   // image feats
    const float* __restrict__ q,
    const float* __restrict__ oW, const float* __restrict__ wW,
    const float* __restrict__ outW,
    unsigned short* __restrict__ ftout,
    unsigned short* __restrict__ qh,    unsigned short* __restrict__ ql,
    unsigned short* __restrict__ oWth,  unsigned short* __restrict__ oWtl,
    unsigned short* __restrict__ wWth,  unsigned short* __restrict__ wWtl,
    unsigned short* __restrict__ outWth,unsigned short* __restrict__ outWtl) {
  __shared__ float tile[64][65];
  const int tid = threadIdx.x;
  if (blockIdx.x < TRANS_BLKS) {
    const int cam = blockIdx.x / 94;
    const int px0 = (blockIdx.x % 94) * 64;
    const int lpx = tid & 63;
    const int cg  = tid >> 6;
    const int px  = px0 + lpx;
    const bool pv = px < NPIX;

    for (int c0 = 0; c0 < 256; c0 += 64) {
#pragma unroll
      for (int i = 0; i < 16; ++i) {
        int cc = cg * 16 + i;
        tile[lpx][cc] = pv ? in[(cam * 256 + c0 + cc) * NPIX + px] : 0.f;
      }
      __syncthreads();
      const int wc = tid & 63;
      const int pg = tid >> 6;
#pragma unroll
      for (int i = 0; i < 16; ++i) {
        int lp = pg * 16 + i;
        int gpx = px0 + lp;
        if (gpx < NPIX)
          ftout[(size_t)(cam * NPIX + gpx) * 256 + c0 + wc] = f2bf(tile[lp][wc]);
      }
      __syncthreads();
    }
    return;
  }
  const int b = blockIdx.x - TRANS_BLKS;
  const int k = tid;
  float v; unsigned short *dh, *dl; int idx;
  if (b < N_Q) {
    v = q[b * 256 + k]; dh = qh; dl = ql; idx = b * 256 + k;
  } else if (b < N_Q + 256) {
    int nn = b - N_Q; v = oW[k * 256 + nn]; dh = oWth; dl = oWtl; idx = nn * 256 + k;
  } else if (b < N_Q + 384) {
    int nn = b - N_Q - 256; v = wW[k * 128 + nn]; dh = wWth; dl = wWtl; idx = nn * 256 + k;
  } else {
    int nn = b - N_Q - 384; v = outW[k * 256 + nn]; dh = outWth; dl = outWtl; idx = nn * 256 + k;
  }
  unsigned short hv = f2bf(v);
  dh[idx] = hv;
  dl[idx] = f2bf(v - bf2f(hv));
}

// ---------------------------------------------------------------------------
// MFMA GEMM body: bf16 hi/lo split, C = A @ Bt^T + bias. No LDS, full unroll.
// ---------------------------------------------------------------------------
__device__ __forceinline__ void gemm_body(
    const unsigned short* __restrict__ Ah, const unsigned short* __restrict__ Al,
    const unsigned short* __restrict__ Bh, const unsigned short* __restrict__ Bl,
    const float* __restrict__ bias, float* __restrict__ C,
    int M, int N, int mode, int bm, int bn, int tid) {
  const int l = tid & 63, w = tid >> 6;
  const int wm = w >> 1, wn = w & 1;
  const int lr = l & 15;
  const int lk = (l >> 4) * 8;

  const int am0 = min(bm + wm * 32 + lr, M - 1);
  const int am1 = min(bm + wm * 32 + 16 + lr, M - 1);
  const int bn0 = bn + wn * 32 + lr;
  const int bn1 = bn0 + 16;

  const bf16x8* pah0 = (const bf16x8*)(Ah + (size_t)am0 * 256 + lk);
  const bf16x8* pah1 = (const bf16x8*)(Ah + (size_t)am1 * 256 + lk);
  const bf16x8* pal0 = (const bf16x8*)(Al + (size_t)am0 * 256 + lk);
  const bf16x8* pal1 = (const bf16x8*)(Al + (size_t)am1 * 256 + lk);
  const bf16x8* pbh0 = (const bf16x8*)(Bh + (size_t)bn0 * 256 + lk);
  const bf16x8* pbh1 = (const bf16x8*)(Bh + (size_t)bn1 * 256 + lk);
  const bf16x8* pbl0 = (const bf16x8*)(Bl + (size_t)bn0 * 256 + lk);
  const bf16x8* pbl1 = (const bf16x8*)(Bl + (size_t)bn1 * 256 + lk);

  f32x4 acc00 = {}, acc01 = {}, acc10 = {}, acc11 = {};

#pragma unroll
  for (int ks = 0; ks < 8; ++ks) {
    bf16x8 ah0 = pah0[ks * 4], ah1 = pah1[ks * 4];
    bf16x8 al0 = pal0[ks * 4], al1 = pal1[ks * 4];
    bf16x8 bh0 = pbh0[ks * 4], bh1 = pbh1[ks * 4];
    bf16x8 bl0 = pbl0[ks * 4], bl1 = pbl1[ks * 4];
    acc00 = __builtin_amdgcn_mfma_f32_16x16x32_bf16(ah0, bh0, acc00, 0, 0, 0);
    acc00 = __builtin_amdgcn_mfma_f32_16x16x32_bf16(ah0, bl0, acc00, 0, 0, 0);
    acc00 = __builtin_amdgcn_mfma_f32_16x16x32_bf16(al0, bh0, acc00, 0, 0, 0);
    acc01 = __builtin_amdgcn_mfma_f32_16x16x32_bf16(ah0, bh1, acc01, 0, 0, 0);
    acc01 = __builtin_amdgcn_mfma_f32_16x16x32_bf16(ah0, bl1, acc01, 0, 0, 0);
    acc01 = __builtin_amdgcn_mfma_f32_16x16x32_bf16(al0, bh1, acc01, 0, 0, 0);
    acc10 = __builtin_amdgcn_mfma_f32_16x16x32_bf16(ah1, bh0, acc10, 0, 0, 0);
    acc10 = __builtin_amdgcn_mfma_f32_16x16x32_bf16(ah1, bl0, acc10, 0, 0, 0);
    acc10 = __builtin_amdgcn_mfma_f32_16x16x32_bf16(al1, bh0, acc10, 0, 0, 0);
    acc11 = __builtin_amdgcn_mfma_f32_16x16x32_bf16(ah1, bh1, acc11, 0, 0, 0);
    acc11 = __builtin_amdgcn_mfma_f32_16x16x32_bf16(ah1, bl1, acc11, 0, 0, 0);
    acc11 = __builtin_amdgcn_mfma_f32_16x16x32_bf16(al1, bh1, acc11, 0, 0, 0);
  }

  const float bias0 = bias[bn + wn * 32 + lr];
  const float bias1 = bias[bn + wn * 32 + 16 + lr];
  const int row0 = bm + wm * 32 + (l >> 4) * 4;
  const int col0 = bn + wn * 32 + lr;
#pragma unroll
  for (int r = 0; r < 4; ++r) {
    int rowA = row0 + r, rowB = row0 + 16 + r;
    float v00 = acc00[r] + bias0, v01 = acc01[r] + bias1;
    float v10 = acc10[r] + bias0, v11 = acc11[r] + bias1;
    if (mode == 1) {
      v00 = tanhf(v00) * 0.12f; v01 = tanhf(v01) * 0.12f;
      v10 = tanhf(v10) * 0.12f; v11 = tanhf(v11) * 0.12f;
    }
    if (rowA < M) {
      C[(size_t)rowA * N + col0] = v00;
      C[(size_t)rowA * N + col0 + 16] = v01;
    }
    if (rowB < M) {
      C[(size_t)rowB * N + col0] = v10;
      C[(size_t)rowB * N + col0 + 16] = v11;
    }
  }
}

// Fused offset+logit GEMMs: blocks_y 0..3 -> offsets (tanh), 4..5 -> logits.
__global__ __launch_bounds__(256) void gemm12_k(
    const unsigned short* __restrict__ Ah, const unsigned short* __restrict__ Al,
    const unsigned short* __restrict__ B1h, const unsigned short* __restrict__ B1l,
    const float* __restrict__ b1, float* __restrict__ C1,
    const unsigned short* __restrict__ B2h, const unsigned short* __restrict__ B2l,
    const float* __restrict__ b2, float* __restrict__ C2) {
  const int by = blockIdx.y;
  if (by < 4)
    gemm_body(Ah, Al, B1h, B1l, b1, C1, N_Q, 256, 1,
              blockIdx.x * 64, by * 64, threadIdx.x);
  else
    gemm_body(Ah, Al, B2h, B2l, b2, C2, N_Q, 128, 0,
              blockIdx.x * 64, (by - 4) * 64, threadIdx.x);
}

__global__ __launch_bounds__(256) void gemm_out_k(
    const unsigned short* __restrict__ Ah, const unsigned short* __restrict__ Al,
    const unsigned short* __restrict__ Bh, const unsigned short* __restrict__ Bl,
    const float* __restrict__ bias, float* __restrict__ C) {
  gemm_body(Ah, Al, Bh, Bl, bias, C, N_Q, 256, 0,
            blockIdx.x * 64, blockIdx.y * 64, threadIdx.x);
}

// ---------------------------------------------------------------------------
// Per-cam deformable sampling (cam-major grid for L2 residency: one cam's
// map = 3.07 MB < 4 MiB XCD L2). Block = 2 queries x 128 threads, ONE cam.
// Writes f32 partial sums; invisible (q,cam) blocks exit (partial unread).
// ---------------------------------------------------------------------------
__global__ __launch_bounds__(256) void sample_cam(
    const unsigned short* __restrict__ ft, // (6,6000,256) bf16
    const float* __restrict__ offs,        // (N,256)
    const float* __restrict__ wlog,        // (N,128)
    const float* __restrict__ refp,        // (6,N,4,2)
    const int*   __restrict__ mask,        // (6,N,4)
    float* __restrict__ partial) {         // (6,N,256) f32
  const int tid = threadIdx.x;
  const int sub = tid >> 7;
  const int t   = tid & 127;
  const int cam = blockIdx.x / (N_Q / 2);
  const int n   = (blockIdx.x % (N_Q / 2)) * 2 + sub;
  const int h   = t >> 4;
  const int p   = t & 15;          // phase-A point
  const int pp  = p >> 2;
  const int c   = (t >> 2) & 3;    // phase-B corner
  const int ch  = t & 3;           // phase-B channel chunk

  const int vis = mask[(cam * N_Q + n) * 4 + pp];
  const unsigned long long bal = __ballot(vis != 0);
  if (!(bal & 0x1111ULL)) return;  // query invisible in this cam

  __shared__ float spt[2][1216];
  float* lds = spt[sub];
  unsigned int* ldsu = reinterpret_cast<unsigned int*>(lds);

  const float2 off = reinterpret_cast<const float2*>(offs)[n * 128 + t];
  const float logit = wlog[n * 128 + t];
  const uint4* ftq = reinterpret_cast<const uint4*>(ft);

  const int abase = h * 152 + p * 9;
  const int rbase = h * 152;
  const unsigned gbase = (unsigned)(h * 4 + ch);

  // masked softmax over the 16 points of this head
  float val = vis ? logit : -1e30f;
#pragma unroll
  for (int m = 8; m >= 1; m >>= 1)
    val = fmaxf(val, __shfl_xor(val, m, 16));
  float e = vis ? __expf(logit - val) : 0.f;
  float s = e;
#pragma unroll
  for (int m = 8; m >= 1; m >>= 1)
    s += __shfl_xor(s, m, 16);
  const float wgt = e / fmaxf(s, 1e-6f);

  // Phase A: this thread's point -> corner weights + pixel indices
  const float2 ref = reinterpret_cast<const float2*>(refp)[(cam * N_Q + n) * 4 + pp];
  const float x = fmaf(ref.x + off.x, (float)WIMG, -0.5f);
  const float y = fmaf(ref.y + off.y, (float)HIMG, -0.5f);
  const float x0f = floorf(x), y0f = floorf(y);
  const float wx = x - x0f, wy = y - y0f;
  const int x0 = (int)x0f, y0 = (int)y0f;
  const int x1 = x0 + 1, y1 = y0 + 1;
  const float mx0 = (x0 >= 0 && x0 < WIMG) ? 1.f : 0.f;
  const float mx1 = (x1 >= 0 && x1 < WIMG) ? 1.f : 0.f;
  const float my0 = (y0 >= 0 && y0 < HIMG) ? 1.f : 0.f;
  const float my1 = (y1 >= 0 && y1 < HIMG) ? 1.f : 0.f;
  const int xc0 = min(max(x0, 0), WIMG - 1);
  const int xc1 = min(max(x1, 0), WIMG - 1);
  const int yc0 = min(max(y0, 0), HIMG - 1);
  const int yc1 = min(max(y1, 0), HIMG - 1);
  lds[abase + 0] = (1.f - wx) * (1.f - wy) * mx0 * my0 * wgt;
  lds[abase + 1] = wx * (1.f - wy) * mx1 * my0 * wgt;
  lds[abase + 2] = (1.f - wx) * wy * mx0 * my1 * wgt;
  lds[abase + 3] = wx * wy * mx1 * my1 * wgt;
  ldsu[abase + 4] = (unsigned)(yc0 * WIMG + xc0);
  ldsu[abase + 5] = (unsigned)(yc0 * WIMG + xc1);
  ldsu[abase + 6] = (unsigned)(yc1 * WIMG + xc0);
  ldsu[abase + 7] = (unsigned)(yc1 * WIMG + xc1);
  __builtin_amdgcn_wave_barrier();

  // Phase B: issue ALL visible pillars' uint4 gathers, then consume.
  float acc[8] = {0.f, 0.f, 0.f, 0.f, 0.f, 0.f, 0.f, 0.f};
  const unsigned camq = (unsigned)cam * (NPIX * 32);
  const bool pv0 = (bal      ) & 1ULL;
  const bool pv1 = (bal >>  4) & 1ULL;
  const bool pv2 = (bal >>  8) & 1ULL;
  const bool pv3 = (bal >> 12) & 1ULL;
  uint4 u0[4], u1[4], u2[4], u3[4];

#define ISSUE(U, P)                                                          \
  if (pv##P) {                                                               \
    _Pragma("unroll")                                                        \
    for (int pn = 0; pn < 4; ++pn) {                                         \
      const unsigned pix = ldsu[rbase + ((P) * 4 + pn) * 9 + 4 + c];         \
      U[pn] = ftq[camq + pix * 32u + gbase];                                 \
    }                                                                        \
  }
  ISSUE(u0, 0) ISSUE(u1, 1) ISSUE(u2, 2) ISSUE(u3, 3)

#define CONSUME(U, P)                                                        \
  if (pv##P) {                                                               \
    _Pragma("unroll")                                                        \
    for (int pn = 0; pn < 4; ++pn) {                                         \
      const float wv = lds[rbase + ((P) * 4 + pn) * 9 + c];                  \
      acc[0] = fmaf(bf16lo(U[pn].x), wv, acc[0]);                            \
      acc[1] = fmaf(bf16hi(U[pn].x), wv, acc[1]);                            \
      acc[2] = fmaf(bf16lo(U[pn].y), wv, acc[2]);                            \
      acc[3] = fmaf(bf16hi(U[pn].y), wv, acc[3]);                            \
      acc[4] = fmaf(bf16lo(U[pn].z), wv, acc[4]);                            \
      acc[5] = fmaf(bf16hi(U[pn].z), wv, acc[5]);                            \
      acc[6] = fmaf(bf16lo(U[pn].w), wv, acc[6]);                            \
      acc[7] = fmaf(bf16hi(U[pn].w), wv, acc[7]);                            \
    }                                                                        \
  }
  CONSUME(u0, 0) CONSUME(u1, 1) CONSUME(u2, 2) CONSUME(u3, 3)
#undef ISSUE
#undef CONSUME

  // reduce over the 4 corner lanes (bits 2-3 of lane id)
#pragma unroll
  for (int j = 0; j < 8; ++j) acc[j] += __shfl_xor(acc[j], 4);
#pragma unroll
  for (int j = 0; j < 8; ++j) acc[j] += __shfl_xor(acc[j], 8);

  if (c == 0) {
    float* pb = partial + ((size_t)cam * N_Q + n) * 256 + h * 32 + ch * 8;
    f32x4 a0 = {acc[0], acc[1], acc[2], acc[3]};
    f32x4 a1 = {acc[4], acc[5], acc[6], acc[7]};
    *reinterpret_cast<f32x4*>(pb)     = a0;
    *reinterpret_cast<f32x4*>(pb + 4) = a1;
  }
}

// ---------------------------------------------------------------------------
// Combine: fused[n] = sum_visible partial[cam][n] / max(count,1); emit bf16
// hi/lo for the out-projection. Block = 2 queries x 128 threads (float2 each).
// ---------------------------------------------------------------------------
__global__ __launch_bounds__(256) void combine_k(
    const float* __restrict__ partial,   // (6,N,256)
    const int*   __restrict__ mask,      // (6,N,4)
    unsigned short* __restrict__ fh,     // (N,256) bf16 hi
    unsigned short* __restrict__ fl) {   // (N,256) bf16 lo
  const int tid = threadIdx.x;
  const int sub = tid >> 7;
  const int t   = tid & 127;
  const int n   = blockIdx.x * 2 + sub;

  __shared__ int sv[2][6];
  if (t < 6) {
    const int4 m4 = *reinterpret_cast<const int4*>(&mask[(t * N_Q + n) * 4]);
    sv[sub][t] = (m4.x | m4.y | m4.z | m4.w) ? 1 : 0;
  }
  __syncthreads();

  float sx = 0.f, sy = 0.f;
  int cnt = 0;
#pragma unroll
  for (int cam = 0; cam < N_CAM; ++cam) {
    if (sv[sub][cam]) {                       // wave-uniform per query
      const float2 v =
          reinterpret_cast<const float2*>(partial)[((size_t)cam * N_Q + n) * 128 + t];
      sx += v.x; sy += v.y; cnt++;
    }
  }
  const float inv = (cnt > 0) ? (1.f / (float)cnt) : 1.f;
  const float v0 = sx * inv, v1 = sy * inv;
  const unsigned short h0 = f2bf(v0), h1 = f2bf(v1);
  const unsigned short l0 = f2bf(v0 - bf2f(h0)), l1 = f2bf(v1 - bf2f(h1));
  reinterpret_cast<unsigned int*>(fh)[n * 128 + t] = (unsigned)h0 | ((unsigned)h1 << 16);
  reinterpret_cast<unsigned int*>(fl)[n * 128 + t] = (unsigned)l0 | ((unsigned)l1 << 16);
}

// ---------------------------------------------------------------------------
extern "C" void kernel_launch(void* const* d_in, const int* in_sizes, int n_in,
                              void* d_out, int out_size, void* d_ws, size_t ws_size,
                              hipStream_t stream) {
  const float* query = (const float*)d_in[0];
  const float* feats = (const float*)d_in[1];
  const float* refp  = (const float*)d_in[2];
  const int*   mask  = (const int*)d_in[3];
  const float* oW    = (const float*)d_in[4];
  const float* ob    = (const float*)d_in[5];
  const float* wW    = (const float*)d_in[6];
  const float* wb    = (const float*)d_in[7];
  const float* outW  = (const float*)d_in[8];
  const float* outb  = (const float*)d_in[9];
  float* out = (float*)d_out;

  char* wsb = (char*)d_ws;
  size_t o = 0;
  unsigned short* ft = (unsigned short*)(wsb + o); o += (size_t)N_CAM * NPIX * 256 * 2;
  unsigned short* qh = (unsigned short*)(wsb + o); o += (size_t)N_Q * 256 * 2;
  unsigned short* ql = (unsigned short*)(wsb + o); o += (size_t)N_Q * 256 * 2;
  unsigned short* fh = (unsigned short*)(wsb + o); o += (size_t)N_Q * 256 * 2;
  unsigned short* fl = (unsigned short*)(wsb + o); o += (size_t)N_Q * 256 * 2;
  unsigned short* oWth  = (unsigned short*)(wsb + o); o += 256 * 256 * 2;
  unsigned short* oWtl  = (unsigned short*)(wsb + o); o += 256 * 256 * 2;
  unsigned short* wWth  = (unsigned short*)(wsb + o); o += 128 * 256 * 2;
  unsigned short* wWtl  = (unsigned short*)(wsb + o); o += 128 * 256 * 2;
  unsigned short* outWth = (unsigned short*)(wsb + o); o += 256 * 256 * 2;
  unsigned short* outWtl = (unsigned short*)(wsb + o); o += 256 * 256 * 2;
  float* offs    = (float*)(wsb + o); o += (size_t)N_Q * 256 * 4;
  float* wlog    = (float*)(wsb + o); o += (size_t)N_Q * 128 * 4;
  float* partial = (float*)(wsb + o); o += (size_t)N_CAM * N_Q * 256 * 4;  // 61.4 MB

  prep_trans_k<<<TRANS_BLKS + N_Q + 640, 256, 0, stream>>>(
      feats, query, oW, wW, outW, ft, qh, ql,
      oWth, oWtl, wWth, wWtl, outWth, outWtl);

  dim3 g12((N_Q + 63) / 64, 6);
  gemm12_k<<<g12, 256, 0, stream>>>(qh, ql, oWth, oWtl, ob, offs,
                                    wWth, wWtl, wb, wlog);

  sample_cam<<<N_CAM * (N_Q / 2), 256, 0, stream>>>(ft, offs, wlog, refp, mask,
                                                    partial);

  combine_k<<<N_Q / 2, 256, 0, stream>>>(partial, mask, fh, fl);

  dim3 g3((N_Q + 63) / 64, 4);
  gemm_out_k<<<g3, 256, 0, stream>>>(fh, fl, outWth, outWtl, outb, out);
}

// Round 7
// 170.211 us; speedup vs baseline: 3.1128x; 1.0001x over previous
//
#include <hip/hip_runtime.h>
#include <hip/hip_bf16.h>

#define N_Q   10000
#define N_CAM 6
#define HIMG  60
#define WIMG  100
#define NPIX  6000

typedef __attribute__((ext_vector_type(4))) float f32x4;
typedef __attribute__((ext_vector_type(2))) float f32x2;
typedef __attribute__((ext_vector_type(8))) short bf16x8;

__device__ __forceinline__ unsigned short f2bf(float x) {
  __hip_bfloat16 b = __float2bfloat16(x);
  return *reinterpret_cast<unsigned short*>(&b);
}
__device__ __forceinline__ float bf2f(unsigned short u) {
  return __uint_as_float(((unsigned)u) << 16);
}
__device__ __forceinline__ float bf16lo(unsigned int u) {
  return __uint_as_float(u << 16);
}
__device__ __forceinline__ float bf16hi(unsigned int u) {
  return __uint_as_float(u & 0xffff0000u);
}
// packed dual-FMA: acc = a * b + acc (2 channels per instruction)
__device__ __forceinline__ void pk_fma(f32x2& acc, f32x2 a, f32x2 b) {
  asm("v_pk_fma_f32 %0, %1, %2, %0" : "+v"(acc) : "v"(a), "v"(b));
}

// ---------------------------------------------------------------------------
// Merged prep: blocks [0,564) transpose feats (6,256,60,100)f32->(6,6000,256)
// bf16 NHWC; blocks [564, ...) decompose query + transposed weights to hi/lo.
// ---------------------------------------------------------------------------
#define TRANS_BLKS (N_CAM * 94)

__global__ __launch_bounds__(256) void prep_trans_k(
    const float* __restrict__ in,   // image feats
    const float* __restrict__ q,
    const float* __restrict__ oW, const float* __restrict__ wW,
    const float* __restrict__ outW,
    unsigned short* __restrict__ ftout,
    unsigned short* __restrict__ qh,    unsigned short* __restrict__ ql,
    unsigned short* __restrict__ oWth,  unsigned short* __restrict__ oWtl,
    unsigned short* __restrict__ wWth,  unsigned short* __restrict__ wWtl,
    unsigned short* __restrict__ outWth,unsigned short* __restrict__ outWtl) {
  __shared__ float tile[64][65];
  const int tid = threadIdx.x;
  if (blockIdx.x < TRANS_BLKS) {
    const int cam = blockIdx.x / 94;
    const int px0 = (blockIdx.x % 94) * 64;
    const int lpx = tid & 63;
    const int cg  = tid >> 6;
    const int px  = px0 + lpx;
    const bool pv = px < NPIX;

    for (int c0 = 0; c0 < 256; c0 += 64) {
#pragma unroll
      for (int i = 0; i < 16; ++i) {
        int cc = cg * 16 + i;
        tile[lpx][cc] = pv ? in[(cam * 256 + c0 + cc) * NPIX + px] : 0.f;
      }
      __syncthreads();
      const int wc = tid & 63;
      const int pg = tid >> 6;
#pragma unroll
      for (int i = 0; i < 16; ++i) {
        int lp = pg * 16 + i;
        int gpx = px0 + lp;
        if (gpx < NPIX)
          ftout[(size_t)(cam * NPIX + gpx) * 256 + c0 + wc] = f2bf(tile[lp][wc]);
      }
      __syncthreads();
    }
    return;
  }
  const int b = blockIdx.x - TRANS_BLKS;
  const int k = tid;
  float v; unsigned short *dh, *dl; int idx;
  if (b < N_Q) {
    v = q[b * 256 + k]; dh = qh; dl = ql; idx = b * 256 + k;
  } else if (b < N_Q + 256) {
    int nn = b - N_Q; v = oW[k * 256 + nn]; dh = oWth; dl = oWtl; idx = nn * 256 + k;
  } else if (b < N_Q + 384) {
    int nn = b - N_Q - 256; v = wW[k * 128 + nn]; dh = wWth; dl = wWtl; idx = nn * 256 + k;
  } else {
    int nn = b - N_Q - 384; v = outW[k * 256 + nn]; dh = outWth; dl = outWtl; idx = nn * 256 + k;
  }
  unsigned short hv = f2bf(v);
  dh[idx] = hv;
  dl[idx] = f2bf(v - bf2f(hv));
}

// ---------------------------------------------------------------------------
// MFMA GEMM body: bf16 hi/lo split, C = A @ Bt^T + bias. No LDS, full unroll.
// mode 0: none  1: tanh(v)*0.12  2: exp(v)  (logits stored pre-exponentiated)
// ---------------------------------------------------------------------------
__device__ __forceinline__ void gemm_body(
    const unsigned short* __restrict__ Ah, const unsigned short* __restrict__ Al,
    const unsigned short* __restrict__ Bh, const unsigned short* __restrict__ Bl,
    const float* __restrict__ bias, float* __restrict__ C,
    int M, int N, int mode, int bm, int bn, int tid) {
  const int l = tid & 63, w = tid >> 6;
  const int wm = w >> 1, wn = w & 1;
  const int lr = l & 15;
  const int lk = (l >> 4) * 8;

  const int am0 = min(bm + wm * 32 + lr, M - 1);
  const int am1 = min(bm + wm * 32 + 16 + lr, M - 1);
  const int bn0 = bn + wn * 32 + lr;
  const int bn1 = bn0 + 16;

  const bf16x8* pah0 = (const bf16x8*)(Ah + (size_t)am0 * 256 + lk);
  const bf16x8* pah1 = (const bf16x8*)(Ah + (size_t)am1 * 256 + lk);
  const bf16x8* pal0 = (const bf16x8*)(Al + (size_t)am0 * 256 + lk);
  const bf16x8* pal1 = (const bf16x8*)(Al + (size_t)am1 * 256 + lk);
  const bf16x8* pbh0 = (const bf16x8*)(Bh + (size_t)bn0 * 256 + lk);
  const bf16x8* pbh1 = (const bf16x8*)(Bh + (size_t)bn1 * 256 + lk);
  const bf16x8* pbl0 = (const bf16x8*)(Bl + (size_t)bn0 * 256 + lk);
  const bf16x8* pbl1 = (const bf16x8*)(Bl + (size_t)bn1 * 256 + lk);

  f32x4 acc00 = {}, acc01 = {}, acc10 = {}, acc11 = {};

#pragma unroll
  for (int ks = 0; ks < 8; ++ks) {
    bf16x8 ah0 = pah0[ks * 4], ah1 = pah1[ks * 4];
    bf16x8 al0 = pal0[ks * 4], al1 = pal1[ks * 4];
    bf16x8 bh0 = pbh0[ks * 4], bh1 = pbh1[ks * 4];
    bf16x8 bl0 = pbl0[ks * 4], bl1 = pbl1[ks * 4];
    acc00 = __builtin_amdgcn_mfma_f32_16x16x32_bf16(ah0, bh0, acc00, 0, 0, 0);
    acc00 = __builtin_amdgcn_mfma_f32_16x16x32_bf16(ah0, bl0, acc00, 0, 0, 0);
    acc00 = __builtin_amdgcn_mfma_f32_16x16x32_bf16(al0, bh0, acc00, 0, 0, 0);
    acc01 = __builtin_amdgcn_mfma_f32_16x16x32_bf16(ah0, bh1, acc01, 0, 0, 0);
    acc01 = __builtin_amdgcn_mfma_f32_16x16x32_bf16(ah0, bl1, acc01, 0, 0, 0);
    acc01 = __builtin_amdgcn_mfma_f32_16x16x32_bf16(al0, bh1, acc01, 0, 0, 0);
    acc10 = __builtin_amdgcn_mfma_f32_16x16x32_bf16(ah1, bh0, acc10, 0, 0, 0);
    acc10 = __builtin_amdgcn_mfma_f32_16x16x32_bf16(ah1, bl0, acc10, 0, 0, 0);
    acc10 = __builtin_amdgcn_mfma_f32_16x16x32_bf16(al1, bh0, acc10, 0, 0, 0);
    acc11 = __builtin_amdgcn_mfma_f32_16x16x32_bf16(ah1, bh1, acc11, 0, 0, 0);
    acc11 = __builtin_amdgcn_mfma_f32_16x16x32_bf16(ah1, bl1, acc11, 0, 0, 0);
    acc11 = __builtin_amdgcn_mfma_f32_16x16x32_bf16(al1, bh1, acc11, 0, 0, 0);
  }

  const float bias0 = bias[bn + wn * 32 + lr];
  const float bias1 = bias[bn + wn * 32 + 16 + lr];
  const int row0 = bm + wm * 32 + (l >> 4) * 4;
  const int col0 = bn + wn * 32 + lr;
#pragma unroll
  for (int r = 0; r < 4; ++r) {
    int rowA = row0 + r, rowB = row0 + 16 + r;
    float v00 = acc00[r] + bias0, v01 = acc01[r] + bias1;
    float v10 = acc10[r] + bias0, v11 = acc11[r] + bias1;
    if (mode == 1) {
      v00 = tanhf(v00) * 0.12f; v01 = tanhf(v01) * 0.12f;
      v10 = tanhf(v10) * 0.12f; v11 = tanhf(v11) * 0.12f;
    } else if (mode == 2) {
      v00 = __expf(v00); v01 = __expf(v01);
      v10 = __expf(v10); v11 = __expf(v11);
    }
    if (rowA < M) {
      C[(size_t)rowA * N + col0] = v00;
      C[(size_t)rowA * N + col0 + 16] = v01;
    }
    if (rowB < M) {
      C[(size_t)rowB * N + col0] = v10;
      C[(size_t)rowB * N + col0 + 16] = v11;
    }
  }
}

// Fused offset+logit GEMMs. N-tile in blockIdx.x so consecutive blocks share
// the same A-panel (L2 reuse); m-tile in blockIdx.y.
// blockIdx.x 0..3 -> offsets (tanh), 4..5 -> logits (exp).
__global__ __launch_bounds__(256) void gemm12_k(
    const unsigned short* __restrict__ Ah, const unsigned short* __restrict__ Al,
    const unsigned short* __restrict__ B1h, const unsigned short* __restrict__ B1l,
    const float* __restrict__ b1, float* __restrict__ C1,
    const unsigned short* __restrict__ B2h, const unsigned short* __restrict__ B2l,
    const float* __restrict__ b2, float* __restrict__ C2) {
  const int by = blockIdx.x;
  if (by < 4)
    gemm_body(Ah, Al, B1h, B1l, b1, C1, N_Q, 256, 1,
              blockIdx.y * 64, by * 64, threadIdx.x);
  else
    gemm_body(Ah, Al, B2h, B2l, b2, C2, N_Q, 128, 2,
              blockIdx.y * 64, (by - 4) * 64, threadIdx.x);
}

__global__ __launch_bounds__(256) void gemm_out_k(
    const unsigned short* __restrict__ Ah, const unsigned short* __restrict__ Al,
    const unsigned short* __restrict__ Bh, const unsigned short* __restrict__ Bl,
    const float* __restrict__ bias, float* __restrict__ C) {
  gemm_body(Ah, Al, Bh, Bl, bias, C, N_Q, 256, 0,
            blockIdx.y * 64, blockIdx.x * 64, threadIdx.x);
}

// ---------------------------------------------------------------------------
// Per-cam deformable sampling (cam-major grid for L2 residency: one cam's
// map = 3.07 MB < 4 MiB XCD L2). Block = 2 queries x 128 threads, ONE cam.
// wlog holds PRE-EXPONENTIATED logits (softmax = E*vis/sum, no max needed).
// Phase B accumulates channel pairs with v_pk_fma_f32.
// ---------------------------------------------------------------------------
__global__ __launch_bounds__(256) void sample_cam(
    const unsigned short* __restrict__ ft, // (6,6000,256) bf16
    const float* __restrict__ offs,        // (N,256)
    const float* __restrict__ wlog,        // (N,128)  E=exp(logit)
    const float* __restrict__ refp,        // (6,N,4,2)
    const int*   __restrict__ mask,        // (6,N,4)
    float* __restrict__ partial) {         // (6,N,256) f32
  const int tid = threadIdx.x;
  const int sub = tid >> 7;
  const int t   = tid & 127;
  const int cam = blockIdx.x / (N_Q / 2);
  const int n   = (blockIdx.x % (N_Q / 2)) * 2 + sub;
  const int h   = t >> 4;
  const int p   = t & 15;          // phase-A point
  const int pp  = p >> 2;
  const int c   = (t >> 2) & 3;    // phase-B corner
  const int ch  = t & 3;           // phase-B channel chunk

  const int vis = mask[(cam * N_Q + n) * 4 + pp];
  const unsigned long long bal = __ballot(vis != 0);
  if (!(bal & 0x1111ULL)) return;  // query invisible in this cam

  __shared__ float spt[2][1216];
  float* lds = spt[sub];
  unsigned int* ldsu = reinterpret_cast<unsigned int*>(lds);

  const float2 off = reinterpret_cast<const float2*>(offs)[n * 128 + t];
  const float E = wlog[n * 128 + t];
  const uint4* ftq = reinterpret_cast<const uint4*>(ft);

  const int abase = h * 152 + p * 9;
  const int rbase = h * 152;
  const unsigned gbase = (unsigned)(h * 4 + ch);

  // masked softmax (pre-exponentiated): w = E*vis / sum(E*vis)
  float e = vis ? E : 0.f;
  float s = e;
#pragma unroll
  for (int m = 8; m >= 1; m >>= 1)
    s += __shfl_xor(s, m, 16);
  const float wgt = e / fmaxf(s, 1e-6f);

  // Phase A: this thread's point -> corner weights + pixel indices
  const float2 ref = reinterpret_cast<const float2*>(refp)[(cam * N_Q + n) * 4 + pp];
  const float x = fmaf(ref.x + off.x, (float)WIMG, -0.5f);
  const float y = fmaf(ref.y + off.y, (float)HIMG, -0.5f);
  const float x0f = floorf(x), y0f = floorf(y);
  const float wx = x - x0f, wy = y - y0f;
  const int x0 = (int)x0f, y0 = (int)y0f;
  const int x1 = x0 + 1, y1 = y0 + 1;
  const float mx0 = (x0 >= 0 && x0 < WIMG) ? 1.f : 0.f;
  const float mx1 = (x1 >= 0 && x1 < WIMG) ? 1.f : 0.f;
  const float my0 = (y0 >= 0 && y0 < HIMG) ? 1.f : 0.f;
  const float my1 = (y1 >= 0 && y1 < HIMG) ? 1.f : 0.f;
  const int xc0 = min(max(x0, 0), WIMG - 1);
  const int xc1 = min(max(x1, 0), WIMG - 1);
  const int yc0 = min(max(y0, 0), HIMG - 1);
  const int yc1 = min(max(y1, 0), HIMG - 1);
  lds[abase + 0] = (1.f - wx) * (1.f - wy) * mx0 * my0 * wgt;
  lds[abase + 1] = wx * (1.f - wy) * mx1 * my0 * wgt;
  lds[abase + 2] = (1.f - wx) * wy * mx0 * my1 * wgt;
  lds[abase + 3] = wx * wy * mx1 * my1 * wgt;
  ldsu[abase + 4] = (unsigned)(yc0 * WIMG + xc0);
  ldsu[abase + 5] = (unsigned)(yc0 * WIMG + xc1);
  ldsu[abase + 6] = (unsigned)(yc1 * WIMG + xc0);
  ldsu[abase + 7] = (unsigned)(yc1 * WIMG + xc1);
  __builtin_amdgcn_wave_barrier();

  // Phase B: issue ALL visible pillars' uint4 gathers, then consume (packed).
  f32x2 acc2[4] = {{0.f, 0.f}, {0.f, 0.f}, {0.f, 0.f}, {0.f, 0.f}};
  const unsigned camq = (unsigned)cam * (NPIX * 32);
  const bool pv0 = (bal      ) & 1ULL;
  const bool pv1 = (bal >>  4) & 1ULL;
  const bool pv2 = (bal >>  8) & 1ULL;
  const bool pv3 = (bal >> 12) & 1ULL;
  uint4 u0[4], u1[4], u2[4], u3[4];

#define ISSUE(U, P)                                                          \
  if (pv##P) {                                                               \
    _Pragma("unroll")                                                        \
    for (int pn = 0; pn < 4; ++pn) {                                         \
      const unsigned pix = ldsu[rbase + ((P) * 4 + pn) * 9 + 4 + c];         \
      U[pn] = ftq[camq + pix * 32u + gbase];                                 \
    }                                                                        \
  }
  ISSUE(u0, 0) ISSUE(u1, 1) ISSUE(u2, 2) ISSUE(u3, 3)

#define CONSUME(U, P)                                                        \
  if (pv##P) {                                                               \
    _Pragma("unroll")                                                        \
    for (int pn = 0; pn < 4; ++pn) {                                         \
      const float wv = lds[rbase + ((P) * 4 + pn) * 9 + c];                  \
      const f32x2 w2 = {wv, wv};                                             \
      f32x2 a;                                                               \
      a.x = bf16lo(U[pn].x); a.y = bf16hi(U[pn].x); pk_fma(acc2[0], a, w2);  \
      a.x = bf16lo(U[pn].y); a.y = bf16hi(U[pn].y); pk_fma(acc2[1], a, w2);  \
      a.x = bf16lo(U[pn].z); a.y = bf16hi(U[pn].z); pk_fma(acc2[2], a, w2);  \
      a.x = bf16lo(U[pn].w); a.y = bf16hi(U[pn].w); pk_fma(acc2[3], a, w2);  \
    }                                                                        \
  }
  CONSUME(u0, 0) CONSUME(u1, 1) CONSUME(u2, 2) CONSUME(u3, 3)
#undef ISSUE
#undef CONSUME

  float acc[8];
#pragma unroll
  for (int j = 0; j < 4; ++j) { acc[2 * j] = acc2[j].x; acc[2 * j + 1] = acc2[j].y; }
  // reduce over the 4 corner lanes (bits 2-3 of lane id)
#pragma unroll
  for (int j = 0; j < 8; ++j) acc[j] += __shfl_xor(acc[j], 4);
#pragma unroll
  for (int j = 0; j < 8; ++j) acc[j] += __shfl_xor(acc[j], 8);

  if (c == 0) {
    float* pb = partial + ((size_t)cam * N_Q + n) * 256 + h * 32 + ch * 8;
    f32x4 a0 = {acc[0], acc[1], acc[2], acc[3]};
    f32x4 a1 = {acc[4], acc[5], acc[6], acc[7]};
    *reinterpret_cast<f32x4*>(pb)     = a0;
    *reinterpret_cast<f32x4*>(pb + 4) = a1;
  }
}

// ---------------------------------------------------------------------------
// Combine: fused[n] = sum_visible partial[cam][n] / max(count,1); emit bf16
// hi/lo for the out-projection. Block = 2 queries x 128 threads (float2 each).
// ---------------------------------------------------------------------------
__global__ __launch_bounds__(256) void combine_k(
    const float* __restrict__ partial,   // (6,N,256)
    const int*   __restrict__ mask,      // (6,N,4)
    unsigned short* __restrict__ fh,     // (N,256) bf16 hi
    unsigned short* __restrict__ fl) {   // (N,256) bf16 lo
  const int tid = threadIdx.x;
  const int sub = tid >> 7;
  const int t   = tid & 127;
  const int n   = blockIdx.x * 2 + sub;

  __shared__ int sv[2][6];
  if (t < 6) {
    const int4 m4 = *reinterpret_cast<const int4*>(&mask[(t * N_Q + n) * 4]);
    sv[sub][t] = (m4.x | m4.y | m4.z | m4.w) ? 1 : 0;
  }
  __syncthreads();

  float sx = 0.f, sy = 0.f;
  int cnt = 0;
#pragma unroll
  for (int cam = 0; cam < N_CAM; ++cam) {
    if (sv[sub][cam]) {                       // wave-uniform per query
      const float2 v =
          reinterpret_cast<const float2*>(partial)[((size_t)cam * N_Q + n) * 128 + t];
      sx += v.x; sy += v.y; cnt++;
    }
  }
  const float inv = (cnt > 0) ? (1.f / (float)cnt) : 1.f;
  const float v0 = sx * inv, v1 = sy * inv;
  const unsigned short h0 = f2bf(v0), h1 = f2bf(v1);
  const unsigned short l0 = f2bf(v0 - bf2f(h0)), l1 = f2bf(v1 - bf2f(h1));
  reinterpret_cast<unsigned int*>(fh)[n * 128 + t] = (unsigned)h0 | ((unsigned)h1 << 16);
  reinterpret_cast<unsigned int*>(fl)[n * 128 + t] = (unsigned)l0 | ((unsigned)l1 << 16);
}

// ---------------------------------------------------------------------------
extern "C" void kernel_launch(void* const* d_in, const int* in_sizes, int n_in,
                              void* d_out, int out_size, void* d_ws, size_t ws_size,
                              hipStream_t stream) {
  const float* query = (const float*)d_in[0];
  const float* feats = (const float*)d_in[1];
  const float* refp  = (const float*)d_in[2];
  const int*   mask  = (const int*)d_in[3];
  const float* oW    = (const float*)d_in[4];
  const float* ob    = (const float*)d_in[5];
  const float* wW    = (const float*)d_in[6];
  const float* wb    = (const float*)d_in[7];
  const float* outW  = (const float*)d_in[8];
  const float* outb  = (const float*)d_in[9];
  float* out = (float*)d_out;

  char* wsb = (char*)d_ws;
  size_t o = 0;
  unsigned short* ft = (unsigned short*)(wsb + o); o += (size_t)N_CAM * NPIX * 256 * 2;
  unsigned short* qh = (unsigned short*)(wsb + o); o += (size_t)N_Q * 256 * 2;
  unsigned short* ql = (unsigned short*)(wsb + o); o += (size_t)N_Q * 256 * 2;
  unsigned short* fh = (unsigned short*)(wsb + o); o += (size_t)N_Q * 256 * 2;
  unsigned short* fl = (unsigned short*)(wsb + o); o += (size_t)N_Q * 256 * 2;
  unsigned short* oWth  = (unsigned short*)(wsb + o); o += 256 * 256 * 2;
  unsigned short* oWtl  = (unsigned short*)(wsb + o); o += 256 * 256 * 2;
  unsigned short* wWth  = (unsigned short*)(wsb + o); o += 128 * 256 * 2;
  unsigned short* wWtl  = (unsigned short*)(wsb + o); o += 128 * 256 * 2;
  unsigned short* outWth = (unsigned short*)(wsb + o); o += 256 * 256 * 2;
  unsigned short* outWtl = (unsigned short*)(wsb + o); o += 256 * 256 * 2;
  float* offs    = (float*)(wsb + o); o += (size_t)N_Q * 256 * 4;
  float* wlog    = (float*)(wsb + o); o += (size_t)N_Q * 128 * 4;
  float* partial = (float*)(wsb + o); o += (size_t)N_CAM * N_Q * 256 * 4;  // 61.4 MB

  prep_trans_k<<<TRANS_BLKS + N_Q + 640, 256, 0, stream>>>(
      feats, query, oW, wW, outW, ft, qh, ql,
      oWth, oWtl, wWth, wWtl, outWth, outWtl);

  dim3 g12(6, (N_Q + 63) / 64);
  gemm12_k<<<g12, 256, 0, stream>>>(qh, ql, oWth, oWtl, ob, offs,
                                    wWth, wWtl, wb, wlog);

  sample_cam<<<N_CAM * (N_Q / 2), 256, 0, stream>>>(ft, offs, wlog, refp, mask,
                                                    partial);

  combine_k<<<N_Q / 2, 256, 0, stream>>>(partial, mask, fh, fl);

  dim3 g3(4, (N_Q + 63) / 64);
  gemm_out_k<<<g3, 256, 0, stream>>>(fh, fl, outWth, outWtl, outb, out);
}

// Round 8
// 167.913 us; speedup vs baseline: 3.1554x; 1.0137x over previous
//
#include <hip/hip_runtime.h>
#include <hip/hip_bf16.h>

#define N_Q   10000
#define N_CAM 6
#define HIMG  60
#define WIMG  100
#define NPIX  6000

typedef __attribute__((ext_vector_type(4))) float f32x4;
typedef __attribute__((ext_vector_type(2))) float f32x2;
typedef __attribute__((ext_vector_type(8))) short bf16x8;

__device__ __forceinline__ unsigned short f2bf(float x) {
  __hip_bfloat16 b = __float2bfloat16(x);
  return *reinterpret_cast<unsigned short*>(&b);
}
__device__ __forceinline__ float bf2f(unsigned short u) {
  return __uint_as_float(((unsigned)u) << 16);
}
__device__ __forceinline__ float bf16lo(unsigned int u) {
  return __uint_as_float(u << 16);
}
// packed dual-FMA: acc = a * b + acc (2 channels per instruction)
__device__ __forceinline__ void pk_fma(f32x2& acc, f32x2 a, f32x2 b) {
  asm("v_pk_fma_f32 %0, %1, %2, %0" : "+v"(acc) : "v"(a), "v"(b));
}

// ---------------------------------------------------------------------------
// Merged prep:
//   blocks [0,564)            : transpose feats f32 (6,256,6000) -> bf16 NHWC
//   blocks [564, 564+1250)    : query hi/lo decompose, 8 elems/thread (vec)
//   blocks [1814, 1814+640)   : weight transpose+decompose (scalar, tiny)
// ---------------------------------------------------------------------------
#define TRANS_BLKS (N_CAM * 94)
#define QVEC_BLKS  1250          // 10000*256 / (256 thr * 8 elems)

__global__ __launch_bounds__(256) void prep_trans_k(
    const float* __restrict__ in,   // image feats
    const float* __restrict__ q,
    const float* __restrict__ oW, const float* __restrict__ wW,
    const float* __restrict__ outW,
    unsigned short* __restrict__ ftout,
    unsigned short* __restrict__ qh,    unsigned short* __restrict__ ql,
    unsigned short* __restrict__ oWth,  unsigned short* __restrict__ oWtl,
    unsigned short* __restrict__ wWth,  unsigned short* __restrict__ wWtl,
    unsigned short* __restrict__ outWth,unsigned short* __restrict__ outWtl) {
  __shared__ float tile[64][65];
  const int tid = threadIdx.x;
  if (blockIdx.x < TRANS_BLKS) {
    const int cam = blockIdx.x / 94;
    const int px0 = (blockIdx.x % 94) * 64;
    const int lpx = tid & 63;
    const int cg  = tid >> 6;
    const int px  = px0 + lpx;
    const bool pv = px < NPIX;

    for (int c0 = 0; c0 < 256; c0 += 64) {
#pragma unroll
      for (int i = 0; i < 16; ++i) {
        int cc = cg * 16 + i;
        tile[lpx][cc] = pv ? in[(cam * 256 + c0 + cc) * NPIX + px] : 0.f;
      }
      __syncthreads();
      const int wc = tid & 63;
      const int pg = tid >> 6;
#pragma unroll
      for (int i = 0; i < 16; ++i) {
        int lp = pg * 16 + i;
        int gpx = px0 + lp;
        if (gpx < NPIX)
          ftout[(size_t)(cam * NPIX + gpx) * 256 + c0 + wc] = f2bf(tile[lp][wc]);
      }
      __syncthreads();
    }
    return;
  }
  if (blockIdx.x < TRANS_BLKS + QVEC_BLKS) {
    // vectorized query decompose: 8 consecutive elements per thread
    const int base = ((blockIdx.x - TRANS_BLKS) * 256 + tid) * 8;
    const float4 v0 = *reinterpret_cast<const float4*>(&q[base]);
    const float4 v1 = *reinterpret_cast<const float4*>(&q[base + 4]);
    float v[8] = {v0.x, v0.y, v0.z, v0.w, v1.x, v1.y, v1.z, v1.w};
    unsigned hw[4], lw[4];
#pragma unroll
    for (int j = 0; j < 4; ++j) {
      const unsigned short h0 = f2bf(v[2 * j]),  h1 = f2bf(v[2 * j + 1]);
      const unsigned short l0 = f2bf(v[2 * j] - bf2f(h0));
      const unsigned short l1 = f2bf(v[2 * j + 1] - bf2f(h1));
      hw[j] = (unsigned)h0 | ((unsigned)h1 << 16);
      lw[j] = (unsigned)l0 | ((unsigned)l1 << 16);
    }
    uint4 vh = {hw[0], hw[1], hw[2], hw[3]};
    uint4 vl = {lw[0], lw[1], lw[2], lw[3]};
    reinterpret_cast<uint4*>(qh)[base >> 3] = vh;
    reinterpret_cast<uint4*>(ql)[base >> 3] = vl;
    return;
  }
  // weights: transpose+decompose (small)
  const int b = blockIdx.x - TRANS_BLKS - QVEC_BLKS;
  const int k = tid;
  float v; unsigned short *dh, *dl; int idx;
  if (b < 256) {
    v = oW[k * 256 + b]; dh = oWth; dl = oWtl; idx = b * 256 + k;
  } else if (b < 384) {
    int nn = b - 256; v = wW[k * 128 + nn]; dh = wWth; dl = wWtl; idx = nn * 256 + k;
  } else {
    int nn = b - 384; v = outW[k * 256 + nn]; dh = outWth; dl = outWtl; idx = nn * 256 + k;
  }
  unsigned short hv = f2bf(v);
  dh[idx] = hv;
  dl[idx] = f2bf(v - bf2f(hv));
}

// ---------------------------------------------------------------------------
// MFMA GEMM body: bf16 hi/lo split, C = A @ Bt^T + bias. No LDS, full unroll.
// mode 0: none  1: tanh(v)*0.12  2: exp(v)
// ---------------------------------------------------------------------------
__device__ __forceinline__ void gemm_body(
    const unsigned short* __restrict__ Ah, const unsigned short* __restrict__ Al,
    const unsigned short* __restrict__ Bh, const unsigned short* __restrict__ Bl,
    const float* __restrict__ bias, float* __restrict__ C,
    int M, int N, int mode, int bm, int bn, int tid) {
  const int l = tid & 63, w = tid >> 6;
  const int wm = w >> 1, wn = w & 1;
  const int lr = l & 15;
  const int lk = (l >> 4) * 8;

  const int am0 = min(bm + wm * 32 + lr, M - 1);
  const int am1 = min(bm + wm * 32 + 16 + lr, M - 1);
  const int bn0 = bn + wn * 32 + lr;
  const int bn1 = bn0 + 16;

  const bf16x8* pah0 = (const bf16x8*)(Ah + (size_t)am0 * 256 + lk);
  const bf16x8* pah1 = (const bf16x8*)(Ah + (size_t)am1 * 256 + lk);
  const bf16x8* pal0 = (const bf16x8*)(Al + (size_t)am0 * 256 + lk);
  const bf16x8* pal1 = (const bf16x8*)(Al + (size_t)am1 * 256 + lk);
  const bf16x8* pbh0 = (const bf16x8*)(Bh + (size_t)bn0 * 256 + lk);
  const bf16x8* pbh1 = (const bf16x8*)(Bh + (size_t)bn1 * 256 + lk);
  const bf16x8* pbl0 = (const bf16x8*)(Bl + (size_t)bn0 * 256 + lk);
  const bf16x8* pbl1 = (const bf16x8*)(Bl + (size_t)bn1 * 256 + lk);

  f32x4 acc00 = {}, acc01 = {}, acc10 = {}, acc11 = {};

#pragma unroll
  for (int ks = 0; ks < 8; ++ks) {
    bf16x8 ah0 = pah0[ks * 4], ah1 = pah1[ks * 4];
    bf16x8 al0 = pal0[ks * 4], al1 = pal1[ks * 4];
    bf16x8 bh0 = pbh0[ks * 4], bh1 = pbh1[ks * 4];
    bf16x8 bl0 = pbl0[ks * 4], bl1 = pbl1[ks * 4];
    acc00 = __builtin_amdgcn_mfma_f32_16x16x32_bf16(ah0, bh0, acc00, 0, 0, 0);
    acc00 = __builtin_amdgcn_mfma_f32_16x16x32_bf16(ah0, bl0, acc00, 0, 0, 0);
    acc00 = __builtin_amdgcn_mfma_f32_16x16x32_bf16(al0, bh0, acc00, 0, 0, 0);
    acc01 = __builtin_amdgcn_mfma_f32_16x16x32_bf16(ah0, bh1, acc01, 0, 0, 0);
    acc01 = __builtin_amdgcn_mfma_f32_16x16x32_bf16(ah0, bl1, acc01, 0, 0, 0);
    acc01 = __builtin_amdgcn_mfma_f32_16x16x32_bf16(al0, bh1, acc01, 0, 0, 0);
    acc10 = __builtin_amdgcn_mfma_f32_16x16x32_bf16(ah1, bh0, acc10, 0, 0, 0);
    acc10 = __builtin_amdgcn_mfma_f32_16x16x32_bf16(ah1, bl0, acc10, 0, 0, 0);
    acc10 = __builtin_amdgcn_mfma_f32_16x16x32_bf16(al1, bh0, acc10, 0, 0, 0);
    acc11 = __builtin_amdgcn_mfma_f32_16x16x32_bf16(ah1, bh1, acc11, 0, 0, 0);
    acc11 = __builtin_amdgcn_mfma_f32_16x16x32_bf16(ah1, bl1, acc11, 0, 0, 0);
    acc11 = __builtin_amdgcn_mfma_f32_16x16x32_bf16(al1, bh1, acc11, 0, 0, 0);
  }

  const float bias0 = bias[bn + wn * 32 + lr];
  const float bias1 = bias[bn + wn * 32 + 16 + lr];
  const int row0 = bm + wm * 32 + (l >> 4) * 4;
  const int col0 = bn + wn * 32 + lr;
#pragma unroll
  for (int r = 0; r < 4; ++r) {
    int rowA = row0 + r, rowB = row0 + 16 + r;
    float v00 = acc00[r] + bias0, v01 = acc01[r] + bias1;
    float v10 = acc10[r] + bias0, v11 = acc11[r] + bias1;
    if (mode == 1) {
      v00 = tanhf(v00) * 0.12f; v01 = tanhf(v01) * 0.12f;
      v10 = tanhf(v10) * 0.12f; v11 = tanhf(v11) * 0.12f;
    } else if (mode == 2) {
      v00 = __expf(v00); v01 = __expf(v01);
      v10 = __expf(v10); v11 = __expf(v11);
    }
    if (rowA < M) {
      C[(size_t)rowA * N + col0] = v00;
      C[(size_t)rowA * N + col0 + 16] = v01;
    }
    if (rowB < M) {
      C[(size_t)rowB * N + col0] = v10;
      C[(size_t)rowB * N + col0 + 16] = v11;
    }
  }
}

// Fused offset+logit GEMMs. blockIdx.x 0..3 -> offsets (tanh), 4..5 -> logits.
__global__ __launch_bounds__(256) void gemm12_k(
    const unsigned short* __restrict__ Ah, const unsigned short* __restrict__ Al,
    const unsigned short* __restrict__ B1h, const unsigned short* __restrict__ B1l,
    const float* __restrict__ b1, float* __restrict__ C1,
    const unsigned short* __restrict__ B2h, const unsigned short* __restrict__ B2l,
    const float* __restrict__ b2, float* __restrict__ C2) {
  const int by = blockIdx.x;
  if (by < 4)
    gemm_body(Ah, Al, B1h, B1l, b1, C1, N_Q, 256, 1,
              blockIdx.y * 64, by * 64, threadIdx.x);
  else
    gemm_body(Ah, Al, B2h, B2l, b2, C2, N_Q, 128, 2,
              blockIdx.y * 64, (by - 4) * 64, threadIdx.x);
}

__global__ __launch_bounds__(256) void gemm_out_k(
    const unsigned short* __restrict__ Ah, const unsigned short* __restrict__ Al,
    const unsigned short* __restrict__ Bh, const unsigned short* __restrict__ Bl,
    const float* __restrict__ bias, float* __restrict__ C) {
  gemm_body(Ah, Al, Bh, Bl, bias, C, N_Q, 256, 0,
            blockIdx.y * 64, blockIdx.x * 64, threadIdx.x);
}

// ---------------------------------------------------------------------------
// Per-cam deformable sampling (cam-major grid, L2-resident map).
// Block = 2 queries x 128 threads, ONE cam. wlog = exp(logit).
// Consume uses pk_fma with RAW dword as hi operand (mantissa pollution
// <= 2^-8 rel, quantified safe) -> saves the v_and per channel pair.
// ---------------------------------------------------------------------------
__global__ __launch_bounds__(256) void sample_cam(
    const unsigned short* __restrict__ ft, // (6,6000,256) bf16
    const float* __restrict__ offs,        // (N,256)
    const float* __restrict__ wlog,        // (N,128)  E=exp(logit)
    const float* __restrict__ refp,        // (6,N,4,2)
    const int*   __restrict__ mask,        // (6,N,4)
    float* __restrict__ partial) {         // (6,N,256) f32
  const int tid = threadIdx.x;
  const int sub = tid >> 7;
  const int t   = tid & 127;
  const int cam = blockIdx.x / (N_Q / 2);
  const int n   = (blockIdx.x % (N_Q / 2)) * 2 + sub;
  const int h   = t >> 4;
  const int p   = t & 15;          // phase-A point
  const int pp  = p >> 2;
  const int c   = (t >> 2) & 3;    // phase-B corner
  const int ch  = t & 3;           // phase-B channel chunk

  const int vis = mask[(cam * N_Q + n) * 4 + pp];
  const unsigned long long bal = __ballot(vis != 0);
  if (!(bal & 0x1111ULL)) return;  // query invisible in this cam

  __shared__ float spt[2][1216];
  float* lds = spt[sub];
  unsigned int* ldsu = reinterpret_cast<unsigned int*>(lds);

  const float2 off = reinterpret_cast<const float2*>(offs)[n * 128 + t];
  const float E = wlog[n * 128 + t];
  // per-lane feature base: cam plane + head/chunk offset folded once
  const uint4* ftq2 = reinterpret_cast<const uint4*>(ft)
                      + (size_t)cam * (NPIX * 32) + (unsigned)(h * 4 + ch);

  const int abase = h * 152 + p * 9;
  const int rbase = h * 152;

  // masked softmax (pre-exponentiated): w = E*vis / sum(E*vis)
  float e = vis ? E : 0.f;
  float s = e;
#pragma unroll
  for (int m = 8; m >= 1; m >>= 1)
    s += __shfl_xor(s, m, 16);
  const float wgt = e / fmaxf(s, 1e-6f);

  // Phase A: this thread's point -> corner weights + pixel indices
  const float2 ref = reinterpret_cast<const float2*>(refp)[(cam * N_Q + n) * 4 + pp];
  const float x = fmaf(ref.x + off.x, (float)WIMG, -0.5f);
  const float y = fmaf(ref.y + off.y, (float)HIMG, -0.5f);
  const float x0f = floorf(x), y0f = floorf(y);
  const float wx = x - x0f, wy = y - y0f;
  const int x0 = (int)x0f, y0 = (int)y0f;
  const int x1 = x0 + 1, y1 = y0 + 1;
  const float mx0 = (x0 >= 0 && x0 < WIMG) ? 1.f : 0.f;
  const float mx1 = (x1 >= 0 && x1 < WIMG) ? 1.f : 0.f;
  const float my0 = (y0 >= 0 && y0 < HIMG) ? 1.f : 0.f;
  const float my1 = (y1 >= 0 && y1 < HIMG) ? 1.f : 0.f;
  const int xc0 = min(max(x0, 0), WIMG - 1);
  const int xc1 = min(max(x1, 0), WIMG - 1);
  const int yc0 = min(max(y0, 0), HIMG - 1);
  const int yc1 = min(max(y1, 0), HIMG - 1);
  lds[abase + 0] = (1.f - wx) * (1.f - wy) * mx0 * my0 * wgt;
  lds[abase + 1] = wx * (1.f - wy) * mx1 * my0 * wgt;
  lds[abase + 2] = (1.f - wx) * wy * mx0 * my1 * wgt;
  lds[abase + 3] = wx * wy * mx1 * my1 * wgt;
  ldsu[abase + 4] = (unsigned)(yc0 * WIMG + xc0);
  ldsu[abase + 5] = (unsigned)(yc0 * WIMG + xc1);
  ldsu[abase + 6] = (unsigned)(yc1 * WIMG + xc0);
  ldsu[abase + 7] = (unsigned)(yc1 * WIMG + xc1);
  __builtin_amdgcn_wave_barrier();

  // Phase B: issue ALL visible pillars' uint4 gathers, then consume (packed).
  f32x2 acc2[4] = {{0.f, 0.f}, {0.f, 0.f}, {0.f, 0.f}, {0.f, 0.f}};
  const bool pv0 = (bal      ) & 1ULL;
  const bool pv1 = (bal >>  4) & 1ULL;
  const bool pv2 = (bal >>  8) & 1ULL;
  const bool pv3 = (bal >> 12) & 1ULL;
  uint4 u0[4], u1[4], u2[4], u3[4];

#define ISSUE(U, P)                                                          \
  if (pv##P) {                                                               \
    _Pragma("unroll")                                                        \
    for (int pn = 0; pn < 4; ++pn) {                                         \
      const unsigned pix = ldsu[rbase + ((P) * 4 + pn) * 9 + 4 + c];         \
      U[pn] = ftq2[pix * 32u];                                               \
    }                                                                        \
  }
  ISSUE(u0, 0) ISSUE(u1, 1) ISSUE(u2, 2) ISSUE(u3, 3)

#define CONSUME(U, P)                                                        \
  if (pv##P) {                                                               \
    _Pragma("unroll")                                                        \
    for (int pn = 0; pn < 4; ++pn) {                                         \
      const float wv = lds[rbase + ((P) * 4 + pn) * 9 + c];                  \
      const f32x2 w2 = {wv, wv};                                             \
      f32x2 a;                                                               \
      a.x = bf16lo(U[pn].x); a.y = __uint_as_float(U[pn].x);                 \
      pk_fma(acc2[0], a, w2);                                                \
      a.x = bf16lo(U[pn].y); a.y = __uint_as_float(U[pn].y);                 \
      pk_fma(acc2[1], a, w2);                                                \
      a.x = bf16lo(U[pn].z); a.y = __uint_as_float(U[pn].z);                 \
      pk_fma(acc2[2], a, w2);                                                \
      a.x = bf16lo(U[pn].w); a.y = __uint_as_float(U[pn].w);                 \
      pk_fma(acc2[3], a, w2);                                                \
    }                                                                        \
  }
  CONSUME(u0, 0) CONSUME(u1, 1) CONSUME(u2, 2) CONSUME(u3, 3)
#undef ISSUE
#undef CONSUME

  float acc[8];
#pragma unroll
  for (int j = 0; j < 4; ++j) { acc[2 * j] = acc2[j].x; acc[2 * j + 1] = acc2[j].y; }
  // reduce over the 4 corner lanes (bits 2-3 of lane id)
#pragma unroll
  for (int j = 0; j < 8; ++j) acc[j] += __shfl_xor(acc[j], 4);
#pragma unroll
  for (int j = 0; j < 8; ++j) acc[j] += __shfl_xor(acc[j], 8);

  if (c == 0) {
    float* pb = partial + ((size_t)cam * N_Q + n) * 256 + h * 32 + ch * 8;
    f32x4 a0 = {acc[0], acc[1], acc[2], acc[3]};
    f32x4 a1 = {acc[4], acc[5], acc[6], acc[7]};
    *reinterpret_cast<f32x4*>(pb)     = a0;
    *reinterpret_cast<f32x4*>(pb + 4) = a1;
  }
}

// ---------------------------------------------------------------------------
// Combine (vectorized): 4 queries x 64 lanes per block; float4 partial reads,
// packed uint2 bf16 hi/lo stores.
// ---------------------------------------------------------------------------
__global__ __launch_bounds__(256) void combine_k(
    const float* __restrict__ partial,   // (6,N,256)
    const int*   __restrict__ mask,      // (6,N,4)
    unsigned short* __restrict__ fh,     // (N,256) bf16 hi
    unsigned short* __restrict__ fl) {   // (N,256) bf16 lo
  const int tid  = threadIdx.x;
  const int sub  = tid >> 6;            // query within block (0..3)
  const int lane = tid & 63;
  const int n    = blockIdx.x * 4 + sub;

  __shared__ int sv[4][6];
  if (tid < 24) {
    const int qi = tid / 6, cam = tid - qi * 6;
    const int nn = blockIdx.x * 4 + qi;
    const int4 m4 = *reinterpret_cast<const int4*>(&mask[(cam * N_Q + nn) * 4]);
    sv[qi][cam] = (m4.x | m4.y | m4.z | m4.w) ? 1 : 0;
  }
  __syncthreads();

  f32x4 s4 = {0.f, 0.f, 0.f, 0.f};
  int cnt = 0;
#pragma unroll
  for (int cam = 0; cam < N_CAM; ++cam) {
    if (sv[sub][cam]) {                       // wave-uniform per query
      const f32x4 v = reinterpret_cast<const f32x4*>(partial)
                          [((size_t)cam * N_Q + n) * 64 + lane];
      s4 += v; cnt++;
    }
  }
  const float inv = (cnt > 0) ? (1.f / (float)cnt) : 1.f;
  unsigned short hs[4], ls[4];
#pragma unroll
  for (int j = 0; j < 4; ++j) {
    const float v = s4[j] * inv;
    hs[j] = f2bf(v);
    ls[j] = f2bf(v - bf2f(hs[j]));
  }
  uint2 vh = {(unsigned)hs[0] | ((unsigned)hs[1] << 16),
              (unsigned)hs[2] | ((unsigned)hs[3] << 16)};
  uint2 vl = {(unsigned)ls[0] | ((unsigned)ls[1] << 16),
              (unsigned)ls[2] | ((unsigned)ls[3] << 16)};
  reinterpret_cast<uint2*>(fh)[n * 64 + lane] = vh;
  reinterpret_cast<uint2*>(fl)[n * 64 + lane] = vl;
}

// ---------------------------------------------------------------------------
extern "C" void kernel_launch(void* const* d_in, const int* in_sizes, int n_in,
                              void* d_out, int out_size, void* d_ws, size_t ws_size,
                              hipStream_t stream) {
  const float* query = (const float*)d_in[0];
  const float* feats = (const float*)d_in[1];
  const float* refp  = (const float*)d_in[2];
  const int*   mask  = (const int*)d_in[3];
  const float* oW    = (const float*)d_in[4];
  const float* ob    = (const float*)d_in[5];
  const float* wW    = (const float*)d_in[6];
  const float* wb    = (const float*)d_in[7];
  const float* outW  = (const float*)d_in[8];
  const float* outb  = (const float*)d_in[9];
  float* out = (float*)d_out;

  char* wsb = (char*)d_ws;
  size_t o = 0;
  unsigned short* ft = (unsigned short*)(wsb + o); o += (size_t)N_CAM * NPIX * 256 * 2;
  unsigned short* qh = (unsigned short*)(wsb + o); o += (size_t)N_Q * 256 * 2;
  unsigned short* ql = (unsigned short*)(wsb + o); o += (size_t)N_Q * 256 * 2;
  unsigned short* fh = (unsigned short*)(wsb + o); o += (size_t)N_Q * 256 * 2;
  unsigned short* fl = (unsigned short*)(wsb + o); o += (size_t)N_Q * 256 * 2;
  unsigned short* oWth  = (unsigned short*)(wsb + o); o += 256 * 256 * 2;
  unsigned short* oWtl  = (unsigned short*)(wsb + o); o += 256 * 256 * 2;
  unsigned short* wWth  = (unsigned short*)(wsb + o); o += 128 * 256 * 2;
  unsigned short* wWtl  = (unsigned short*)(wsb + o); o += 128 * 256 * 2;
  unsigned short* outWth = (unsigned short*)(wsb + o); o += 256 * 256 * 2;
  unsigned short* outWtl = (unsigned short*)(wsb + o); o += 256 * 256 * 2;
  float* offs    = (float*)(wsb + o); o += (size_t)N_Q * 256 * 4;
  float* wlog    = (float*)(wsb + o); o += (size_t)N_Q * 128 * 4;
  float* partial = (float*)(wsb + o); o += (size_t)N_CAM * N_Q * 256 * 4;  // 61.4 MB

  prep_trans_k<<<TRANS_BLKS + QVEC_BLKS + 640, 256, 0, stream>>>(
      feats, query, oW, wW, outW, ft, qh, ql,
      oWth, oWtl, wWth, wWtl, outWth, outWtl);

  dim3 g12(6, (N_Q + 63) / 64);
  gemm12_k<<<g12, 256, 0, stream>>>(qh, ql, oWth, oWtl, ob, offs,
                                    wWth, wWtl, wb, wlog);

  sample_cam<<<N_CAM * (N_Q / 2), 256, 0, stream>>>(ft, offs, wlog, refp, mask,
                                                    partial);

  combine_k<<<N_Q / 4, 256, 0, stream>>>(partial, mask, fh, fl);

  dim3 g3(4, (N_Q + 63) / 64);
  gemm_out_k<<<g3, 256, 0, stream>>>(fh, fl, outWth, outWtl, outb, out);
}

// Round 9
// 166.339 us; speedup vs baseline: 3.1852x; 1.0095x over previous
//
#include <hip/hip_runtime.h>
#include <hip/hip_bf16.h>

#define N_Q   10000
#define N_CAM 6
#define HIMG  60
#define WIMG  100
#define NPIX  6000

typedef __attribute__((ext_vector_type(4))) float f32x4;
typedef __attribute__((ext_vector_type(2))) float f32x2;
typedef __attribute__((ext_vector_type(8))) short bf16x8;

__device__ __forceinline__ unsigned short f2bf(float x) {
  __hip_bfloat16 b = __float2bfloat16(x);
  return *reinterpret_cast<unsigned short*>(&b);
}
__device__ __forceinline__ float bf2f(unsigned short u) {
  return __uint_as_float(((unsigned)u) << 16);
}
__device__ __forceinline__ float bf16lo(unsigned int u) {
  return __uint_as_float(u << 16);
}
__device__ __forceinline__ float bf16hi(unsigned int u) {
  return __uint_as_float(u & 0xffff0000u);
}
// packed dual-FMA: acc = a * b + acc (2 channels per instruction)
__device__ __forceinline__ void pk_fma(f32x2& acc, f32x2 a, f32x2 b) {
  asm("v_pk_fma_f32 %0, %1, %2, %0" : "+v"(acc) : "v"(a), "v"(b));
}

// ---------------------------------------------------------------------------
// Merged prep:
//   blocks [0,564)            : transpose feats f32 (6,256,6000) -> bf16 NHWC
//   blocks [564, 564+1250)    : query hi/lo decompose, 8 elems/thread (vec)
//   blocks [1814, 1814+640)   : weight transpose+decompose (scalar, tiny)
// ---------------------------------------------------------------------------
#define TRANS_BLKS (N_CAM * 94)
#define QVEC_BLKS  1250          // 10000*256 / (256 thr * 8 elems)

__global__ __launch_bounds__(256) void prep_trans_k(
    const float* __restrict__ in,   // image feats
    const float* __restrict__ q,
    const float* __restrict__ oW, const float* __restrict__ wW,
    const float* __restrict__ outW,
    unsigned short* __restrict__ ftout,
    unsigned short* __restrict__ qh,    unsigned short* __restrict__ ql,
    unsigned short* __restrict__ oWth,  unsigned short* __restrict__ oWtl,
    unsigned short* __restrict__ wWth,  unsigned short* __restrict__ wWtl,
    unsigned short* __restrict__ outWth,unsigned short* __restrict__ outWtl) {
  __shared__ float tile[64][65];
  const int tid = threadIdx.x;
  if (blockIdx.x < TRANS_BLKS) {
    const int cam = blockIdx.x / 94;
    const int px0 = (blockIdx.x % 94) * 64;
    const int lpx = tid & 63;
    const int cg  = tid >> 6;
    const int px  = px0 + lpx;
    const bool pv = px < NPIX;

    for (int c0 = 0; c0 < 256; c0 += 64) {
#pragma unroll
      for (int i = 0; i < 16; ++i) {
        int cc = cg * 16 + i;
        tile[lpx][cc] = pv ? in[(cam * 256 + c0 + cc) * NPIX + px] : 0.f;
      }
      __syncthreads();
      const int wc = tid & 63;
      const int pg = tid >> 6;
#pragma unroll
      for (int i = 0; i < 16; ++i) {
        int lp = pg * 16 + i;
        int gpx = px0 + lp;
        if (gpx < NPIX)
          ftout[(size_t)(cam * NPIX + gpx) * 256 + c0 + wc] = f2bf(tile[lp][wc]);
      }
      __syncthreads();
    }
    return;
  }
  if (blockIdx.x < TRANS_BLKS + QVEC_BLKS) {
    // vectorized query decompose: 8 consecutive elements per thread
    const int base = ((blockIdx.x - TRANS_BLKS) * 256 + tid) * 8;
    const float4 v0 = *reinterpret_cast<const float4*>(&q[base]);
    const float4 v1 = *reinterpret_cast<const float4*>(&q[base + 4]);
    float v[8] = {v0.x, v0.y, v0.z, v0.w, v1.x, v1.y, v1.z, v1.w};
    unsigned hw[4], lw[4];
#pragma unroll
    for (int j = 0; j < 4; ++j) {
      const unsigned short h0 = f2bf(v[2 * j]),  h1 = f2bf(v[2 * j + 1]);
      const unsigned short l0 = f2bf(v[2 * j] - bf2f(h0));
      const unsigned short l1 = f2bf(v[2 * j + 1] - bf2f(h1));
      hw[j] = (unsigned)h0 | ((unsigned)h1 << 16);
      lw[j] = (unsigned)l0 | ((unsigned)l1 << 16);
    }
    uint4 vh = {hw[0], hw[1], hw[2], hw[3]};
    uint4 vl = {lw[0], lw[1], lw[2], lw[3]};
    reinterpret_cast<uint4*>(qh)[base >> 3] = vh;
    reinterpret_cast<uint4*>(ql)[base >> 3] = vl;
    return;
  }
  // weights: transpose+decompose (small)
  const int b = blockIdx.x - TRANS_BLKS - QVEC_BLKS;
  const int k = tid;
  float v; unsigned short *dh, *dl; int idx;
  if (b < 256) {
    v = oW[k * 256 + b]; dh = oWth; dl = oWtl; idx = b * 256 + k;
  } else if (b < 384) {
    int nn = b - 256; v = wW[k * 128 + nn]; dh = wWth; dl = wWtl; idx = nn * 256 + k;
  } else {
    int nn = b - 384; v = outW[k * 256 + nn]; dh = outWth; dl = outWtl; idx = nn * 256 + k;
  }
  unsigned short hv = f2bf(v);
  dh[idx] = hv;
  dl[idx] = f2bf(v - bf2f(hv));
}

// ---------------------------------------------------------------------------
// MFMA GEMM body: bf16 hi/lo split, C = A @ Bt^T + bias. No LDS, full unroll.
// mode 0: none  1: tanh(v)*0.12  2: exp(v)
// ---------------------------------------------------------------------------
__device__ __forceinline__ void gemm_body(
    const unsigned short* __restrict__ Ah, const unsigned short* __restrict__ Al,
    const unsigned short* __restrict__ Bh, const unsigned short* __restrict__ Bl,
    const float* __restrict__ bias, float* __restrict__ C,
    int M, int N, int mode, int bm, int bn, int tid) {
  const int l = tid & 63, w = tid >> 6;
  const int wm = w >> 1, wn = w & 1;
  const int lr = l & 15;
  const int lk = (l >> 4) * 8;

  const int am0 = min(bm + wm * 32 + lr, M - 1);
  const int am1 = min(bm + wm * 32 + 16 + lr, M - 1);
  const int bn0 = bn + wn * 32 + lr;
  const int bn1 = bn0 + 16;

  const bf16x8* pah0 = (const bf16x8*)(Ah + (size_t)am0 * 256 + lk);
  const bf16x8* pah1 = (const bf16x8*)(Ah + (size_t)am1 * 256 + lk);
  const bf16x8* pal0 = (const bf16x8*)(Al + (size_t)am0 * 256 + lk);
  const bf16x8* pal1 = (const bf16x8*)(Al + (size_t)am1 * 256 + lk);
  const bf16x8* pbh0 = (const bf16x8*)(Bh + (size_t)bn0 * 256 + lk);
  const bf16x8* pbh1 = (const bf16x8*)(Bh + (size_t)bn1 * 256 + lk);
  const bf16x8* pbl0 = (const bf16x8*)(Bl + (size_t)bn0 * 256 + lk);
  const bf16x8* pbl1 = (const bf16x8*)(Bl + (size_t)bn1 * 256 + lk);

  f32x4 acc00 = {}, acc01 = {}, acc10 = {}, acc11 = {};

#pragma unroll
  for (int ks = 0; ks < 8; ++ks) {
    bf16x8 ah0 = pah0[ks * 4], ah1 = pah1[ks * 4];
    bf16x8 al0 = pal0[ks * 4], al1 = pal1[ks * 4];
    bf16x8 bh0 = pbh0[ks * 4], bh1 = pbh1[ks * 4];
    bf16x8 bl0 = pbl0[ks * 4], bl1 = pbl1[ks * 4];
    acc00 = __builtin_amdgcn_mfma_f32_16x16x32_bf16(ah0, bh0, acc00, 0, 0, 0);
    acc00 = __builtin_amdgcn_mfma_f32_16x16x32_bf16(ah0, bl0, acc00, 0, 0, 0);
    acc00 = __builtin_amdgcn_mfma_f32_16x16x32_bf16(al0, bh0, acc00, 0, 0, 0);
    acc01 = __builtin_amdgcn_mfma_f32_16x16x32_bf16(ah0, bh1, acc01, 0, 0, 0);
    acc01 = __builtin_amdgcn_mfma_f32_16x16x32_bf16(ah0, bl1, acc01, 0, 0, 0);
    acc01 = __builtin_amdgcn_mfma_f32_16x16x32_bf16(al0, bh1, acc01, 0, 0, 0);
    acc10 = __builtin_amdgcn_mfma_f32_16x16x32_bf16(ah1, bh0, acc10, 0, 0, 0);
    acc10 = __builtin_amdgcn_mfma_f32_16x16x32_bf16(ah1, bl0, acc10, 0, 0, 0);
    acc10 = __builtin_amdgcn_mfma_f32_16x16x32_bf16(al1, bh0, acc10, 0, 0, 0);
    acc11 = __builtin_amdgcn_mfma_f32_16x16x32_bf16(ah1, bh1, acc11, 0, 0, 0);
    acc11 = __builtin_amdgcn_mfma_f32_16x16x32_bf16(ah1, bl1, acc11, 0, 0, 0);
    acc11 = __builtin_amdgcn_mfma_f32_16x16x32_bf16(al1, bh1, acc11, 0, 0, 0);
  }

  const float bias0 = bias[bn + wn * 32 + lr];
  const float bias1 = bias[bn + wn * 32 + 16 + lr];
  const int row0 = bm + wm * 32 + (l >> 4) * 4;
  const int col0 = bn + wn * 32 + lr;
#pragma unroll
  for (int r = 0; r < 4; ++r) {
    int rowA = row0 + r, rowB = row0 + 16 + r;
    float v00 = acc00[r] + bias0, v01 = acc01[r] + bias1;
    float v10 = acc10[r] + bias0, v11 = acc11[r] + bias1;
    if (mode == 1) {
      v00 = tanhf(v00) * 0.12f; v01 = tanhf(v01) * 0.12f;
      v10 = tanhf(v10) * 0.12f; v11 = tanhf(v11) * 0.12f;
    } else if (mode == 2) {
      v00 = __expf(v00); v01 = __expf(v01);
      v10 = __expf(v10); v11 = __expf(v11);
    }
    if (rowA < M) {
      C[(size_t)rowA * N + col0] = v00;
      C[(size_t)rowA * N + col0 + 16] = v01;
    }
    if (rowB < M) {
      C[(size_t)rowB * N + col0] = v10;
      C[(size_t)rowB * N + col0 + 16] = v11;
    }
  }
}

// Fused offset+logit GEMMs. blockIdx.x 0..3 -> offsets (tanh), 4..5 -> logits.
__global__ __launch_bounds__(256) void gemm12_k(
    const unsigned short* __restrict__ Ah, const unsigned short* __restrict__ Al,
    const unsigned short* __restrict__ B1h, const unsigned short* __restrict__ B1l,
    const float* __restrict__ b1, float* __restrict__ C1,
    const unsigned short* __restrict__ B2h, const unsigned short* __restrict__ B2l,
    const float* __restrict__ b2, float* __restrict__ C2) {
  const int by = blockIdx.x;
  if (by < 4)
    gemm_body(Ah, Al, B1h, B1l, b1, C1, N_Q, 256, 1,
              blockIdx.y * 64, by * 64, threadIdx.x);
  else
    gemm_body(Ah, Al, B2h, B2l, b2, C2, N_Q, 128, 2,
              blockIdx.y * 64, (by - 4) * 64, threadIdx.x);
}

__global__ __launch_bounds__(256) void gemm_out_k(
    const unsigned short* __restrict__ Ah, const unsigned short* __restrict__ Al,
    const unsigned short* __restrict__ Bh, const unsigned short* __restrict__ Bl,
    const float* __restrict__ bias, float* __restrict__ C) {
  gemm_body(Ah, Al, Bh, Bl, bias, C, N_Q, 256, 0,
            blockIdx.y * 64, blockIdx.x * 64, threadIdx.x);
}

// ---------------------------------------------------------------------------
// Per-cam deformable sampling, cam-major, 8 queries per block (4 iter x 2).
// Software pipeline: next iteration's inputs (mask/offs/wlog/refp) prefetched
// before current iteration's gather-consume; double-buffered LDS.
// Partial sums stored as bf16 (halves write + combine-read traffic).
// ---------------------------------------------------------------------------
#define QPB   4
#define QBLKS (N_Q / 2 / QPB)   // 1250 blocks per cam

__global__ __launch_bounds__(256) void sample_cam(
    const unsigned short* __restrict__ ft, // (6,6000,256) bf16
    const float* __restrict__ offs,        // (N,256)
    const float* __restrict__ wlog,        // (N,128)  E=exp(logit)
    const float* __restrict__ refp,        // (6,N,4,2)
    const int*   __restrict__ mask,        // (6,N,4)
    unsigned short* __restrict__ partial) {// (6,N,256) bf16 raw sums
  const int tid = threadIdx.x;
  const int sub = tid >> 7;
  const int t   = tid & 127;
  const int cam = blockIdx.x / QBLKS;
  const int q0  = (blockIdx.x % QBLKS) * QPB;
  const int h   = t >> 4;
  const int p   = t & 15;          // phase-A point
  const int pp  = p >> 2;
  const int c   = (t >> 2) & 3;    // phase-B corner
  const int ch  = t & 3;           // phase-B channel chunk

  __shared__ float spt[2][2][1216];

  const uint4* ftq2 = reinterpret_cast<const uint4*>(ft)
                      + (size_t)cam * (NPIX * 32) + (unsigned)(h * 4 + ch);

  // prefetched inputs for the upcoming iteration
  int n_pf = q0 * 2 + sub;
  int    vis_n = mask[(cam * N_Q + n_pf) * 4 + pp];
  float2 off_n = reinterpret_cast<const float2*>(offs)[n_pf * 128 + t];
  float  E_n   = wlog[n_pf * 128 + t];
  float2 ref_n = reinterpret_cast<const float2*>(refp)[(cam * N_Q + n_pf) * 4 + pp];

  int buf = 0;
  for (int it = 0; it < QPB; ++it) {
    const int n = (q0 + it) * 2 + sub;
    const int    vis = vis_n;
    const float2 off = off_n;
    const float  E   = E_n;
    const float2 ref = ref_n;
    const unsigned long long bal = __ballot(vis != 0);
    if (it + 1 < QPB) {           // issue next iteration's input loads now
      const int n1 = (q0 + it + 1) * 2 + sub;
      vis_n = mask[(cam * N_Q + n1) * 4 + pp];
      off_n = reinterpret_cast<const float2*>(offs)[n1 * 128 + t];
      E_n   = wlog[n1 * 128 + t];
      ref_n = reinterpret_cast<const float2*>(refp)[(cam * N_Q + n1) * 4 + pp];
    }
    if (!(bal & 0x1111ULL)) continue;   // this query invisible in this cam

    float* lds = spt[buf][sub];
    unsigned int* ldsu = reinterpret_cast<unsigned int*>(lds);
    buf ^= 1;

    const int abase = h * 152 + p * 9;
    const int rbase = h * 152;

    // masked softmax (pre-exponentiated): w = E*vis / sum(E*vis)
    float e = vis ? E : 0.f;
    float s = e;
#pragma unroll
    for (int m = 8; m >= 1; m >>= 1)
      s += __shfl_xor(s, m, 16);
    const float wgt = e / fmaxf(s, 1e-6f);

    // Phase A: this thread's point -> corner weights + pixel indices
    const float x = fmaf(ref.x + off.x, (float)WIMG, -0.5f);
    const float y = fmaf(ref.y + off.y, (float)HIMG, -0.5f);
    const float x0f = floorf(x), y0f = floorf(y);
    const float wx = x - x0f, wy = y - y0f;
    const int x0 = (int)x0f, y0 = (int)y0f;
    const int x1 = x0 + 1, y1 = y0 + 1;
    const float mx0 = (x0 >= 0 && x0 < WIMG) ? 1.f : 0.f;
    const float mx1 = (x1 >= 0 && x1 < WIMG) ? 1.f : 0.f;
    const float my0 = (y0 >= 0 && y0 < HIMG) ? 1.f : 0.f;
    const float my1 = (y1 >= 0 && y1 < HIMG) ? 1.f : 0.f;
    const int xc0 = min(max(x0, 0), WIMG - 1);
    const int xc1 = min(max(x1, 0), WIMG - 1);
    const int yc0 = min(max(y0, 0), HIMG - 1);
    const int yc1 = min(max(y1, 0), HIMG - 1);
    lds[abase + 0] = (1.f - wx) * (1.f - wy) * mx0 * my0 * wgt;
    lds[abase + 1] = wx * (1.f - wy) * mx1 * my0 * wgt;
    lds[abase + 2] = (1.f - wx) * wy * mx0 * my1 * wgt;
    lds[abase + 3] = wx * wy * mx1 * my1 * wgt;
    ldsu[abase + 4] = (unsigned)(yc0 * WIMG + xc0);
    ldsu[abase + 5] = (unsigned)(yc0 * WIMG + xc1);
    ldsu[abase + 6] = (unsigned)(yc1 * WIMG + xc0);
    ldsu[abase + 7] = (unsigned)(yc1 * WIMG + xc1);
    __builtin_amdgcn_wave_barrier();

    // Phase B: issue ALL visible pillars' uint4 gathers, then consume.
    f32x2 acc2[4] = {{0.f, 0.f}, {0.f, 0.f}, {0.f, 0.f}, {0.f, 0.f}};
    const bool pv0 = (bal      ) & 1ULL;
    const bool pv1 = (bal >>  4) & 1ULL;
    const bool pv2 = (bal >>  8) & 1ULL;
    const bool pv3 = (bal >> 12) & 1ULL;
    uint4 u0[4], u1[4], u2[4], u3[4];

#define ISSUE(U, P)                                                          \
    if (pv##P) {                                                             \
      _Pragma("unroll")                                                      \
      for (int pn = 0; pn < 4; ++pn) {                                       \
        const unsigned pix = ldsu[rbase + ((P) * 4 + pn) * 9 + 4 + c];       \
        U[pn] = ftq2[pix * 32u];                                             \
      }                                                                      \
    }
    ISSUE(u0, 0) ISSUE(u1, 1) ISSUE(u2, 2) ISSUE(u3, 3)

#define CONSUME(U, P)                                                        \
    if (pv##P) {                                                             \
      _Pragma("unroll")                                                      \
      for (int pn = 0; pn < 4; ++pn) {                                       \
        const float wv = lds[rbase + ((P) * 4 + pn) * 9 + c];                \
        const f32x2 w2 = {wv, wv};                                           \
        f32x2 a;                                                             \
        a.x = bf16lo(U[pn].x); a.y = __uint_as_float(U[pn].x);               \
        pk_fma(acc2[0], a, w2);                                              \
        a.x = bf16lo(U[pn].y); a.y = __uint_as_float(U[pn].y);               \
        pk_fma(acc2[1], a, w2);                                              \
        a.x = bf16lo(U[pn].z); a.y = __uint_as_float(U[pn].z);               \
        pk_fma(acc2[2], a, w2);                                              \
        a.x = bf16lo(U[pn].w); a.y = __uint_as_float(U[pn].w);               \
        pk_fma(acc2[3], a, w2);                                              \
      }                                                                      \
    }
    CONSUME(u0, 0) CONSUME(u1, 1) CONSUME(u2, 2) CONSUME(u3, 3)
#undef ISSUE
#undef CONSUME

    float acc[8];
#pragma unroll
    for (int j = 0; j < 4; ++j) { acc[2 * j] = acc2[j].x; acc[2 * j + 1] = acc2[j].y; }
    // reduce over the 4 corner lanes (bits 2-3 of lane id)
#pragma unroll
    for (int j = 0; j < 8; ++j) acc[j] += __shfl_xor(acc[j], 4);
#pragma unroll
    for (int j = 0; j < 8; ++j) acc[j] += __shfl_xor(acc[j], 8);

    if (c == 0) {
      unsigned w01 = (unsigned)f2bf(acc[0]) | ((unsigned)f2bf(acc[1]) << 16);
      unsigned w23 = (unsigned)f2bf(acc[2]) | ((unsigned)f2bf(acc[3]) << 16);
      unsigned w45 = (unsigned)f2bf(acc[4]) | ((unsigned)f2bf(acc[5]) << 16);
      unsigned w67 = (unsigned)f2bf(acc[6]) | ((unsigned)f2bf(acc[7]) << 16);
      uint4 v = {w01, w23, w45, w67};
      reinterpret_cast<uint4*>(partial)[((size_t)cam * N_Q + n) * 32 + h * 4 + ch] = v;
    }
  }
}

// ---------------------------------------------------------------------------
// Combine: 4 queries x 64 lanes per block; bf16 partial reads (uint2 = 4 ch),
// f32 accumulate, packed bf16 hi/lo stores.
// ---------------------------------------------------------------------------
__global__ __launch_bounds__(256) void combine_k(
    const unsigned short* __restrict__ partial, // (6,N,256) bf16
    const int*   __restrict__ mask,             // (6,N,4)
    unsigned short* __restrict__ fh,            // (N,256) bf16 hi
    unsigned short* __restrict__ fl) {          // (N,256) bf16 lo
  const int tid  = threadIdx.x;
  const int sub  = tid >> 6;            // query within block (0..3)
  const int lane = tid & 63;
  const int n    = blockIdx.x * 4 + sub;

  __shared__ int sv[4][6];
  if (tid < 24) {
    const int qi = tid / 6, cam = tid - qi * 6;
    const int nn = blockIdx.x * 4 + qi;
    const int4 m4 = *reinterpret_cast<const int4*>(&mask[(cam * N_Q + nn) * 4]);
    sv[qi][cam] = (m4.x | m4.y | m4.z | m4.w) ? 1 : 0;
  }
  __syncthreads();

  f32x4 s4 = {0.f, 0.f, 0.f, 0.f};
  int cnt = 0;
#pragma unroll
  for (int cam = 0; cam < N_CAM; ++cam) {
    if (sv[sub][cam]) {                       // wave-uniform per query
      const uint2 v = reinterpret_cast<const uint2*>(partial)
                          [((size_t)cam * N_Q + n) * 64 + lane];
      s4[0] += bf16lo(v.x); s4[1] += bf16hi(v.x);
      s4[2] += bf16lo(v.y); s4[3] += bf16hi(v.y);
      cnt++;
    }
  }
  const float inv = (cnt > 0) ? (1.f / (float)cnt) : 1.f;
  unsigned short hs[4], ls[4];
#pragma unroll
  for (int j = 0; j < 4; ++j) {
    const float v = s4[j] * inv;
    hs[j] = f2bf(v);
    ls[j] = f2bf(v - bf2f(hs[j]));
  }
  uint2 vh = {(unsigned)hs[0] | ((unsigned)hs[1] << 16),
              (unsigned)hs[2] | ((unsigned)hs[3] << 16)};
  uint2 vl = {(unsigned)ls[0] | ((unsigned)ls[1] << 16),
              (unsigned)ls[2] | ((unsigned)ls[3] << 16)};
  reinterpret_cast<uint2*>(fh)[n * 64 + lane] = vh;
  reinterpret_cast<uint2*>(fl)[n * 64 + lane] = vl;
}

// ---------------------------------------------------------------------------
extern "C" void kernel_launch(void* const* d_in, const int* in_sizes, int n_in,
                              void* d_out, int out_size, void* d_ws, size_t ws_size,
                              hipStream_t stream) {
  const float* query = (const float*)d_in[0];
  const float* feats = (const float*)d_in[1];
  const float* refp  = (const float*)d_in[2];
  const int*   mask  = (const int*)d_in[3];
  const float* oW    = (const float*)d_in[4];
  const float* ob    = (const float*)d_in[5];
  const float* wW    = (const float*)d_in[6];
  const float* wb    = (const float*)d_in[7];
  const float* outW  = (const float*)d_in[8];
  const float* outb  = (const float*)d_in[9];
  float* out = (float*)d_out;

  char* wsb = (char*)d_ws;
  size_t o = 0;
  unsigned short* ft = (unsigned short*)(wsb + o); o += (size_t)N_CAM * NPIX * 256 * 2;
  unsigned short* qh = (unsigned short*)(wsb + o); o += (size_t)N_Q * 256 * 2;
  unsigned short* ql = (unsigned short*)(wsb + o); o += (size_t)N_Q * 256 * 2;
  unsigned short* fh = (unsigned short*)(wsb + o); o += (size_t)N_Q * 256 * 2;
  unsigned short* fl = (unsigned short*)(wsb + o); o += (size_t)N_Q * 256 * 2;
  unsigned short* oWth  = (unsigned short*)(wsb + o); o += 256 * 256 * 2;
  unsigned short* oWtl  = (unsigned short*)(wsb + o); o += 256 * 256 * 2;
  unsigned short* wWth  = (unsigned short*)(wsb + o); o += 128 * 256 * 2;
  unsigned short* wWtl  = (unsigned short*)(wsb + o); o += 128 * 256 * 2;
  unsigned short* outWth = (unsigned short*)(wsb + o); o += 256 * 256 * 2;
  unsigned short* outWtl = (unsigned short*)(wsb + o); o += 256 * 256 * 2;
  float* offs    = (float*)(wsb + o); o += (size_t)N_Q * 256 * 4;
  float* wlog    = (float*)(wsb + o); o += (size_t)N_Q * 128 * 4;
  unsigned short* partial = (unsigned short*)(wsb + o);
  o += (size_t)N_CAM * N_Q * 256 * 2;                                      // 30.7 MB

  prep_trans_k<<<TRANS_BLKS + QVEC_BLKS + 640, 256, 0, stream>>>(
      feats, query, oW, wW, outW, ft, qh, ql,
      oWth, oWtl, wWth, wWtl, outWth, outWtl);

  dim3 g12(6, (N_Q + 63) / 64);
  gemm12_k<<<g12, 256, 0, stream>>>(qh, ql, oWth, oWtl, ob, offs,
                                    wWth, wWtl, wb, wlog);

  sample_cam<<<N_CAM * QBLKS, 256, 0, stream>>>(ft, offs, wlog, refp, mask,
                                                partial);

  combine_k<<<N_Q / 4, 256, 0, stream>>>(partial, mask, fh, fl);

  dim3 g3(4, (N_Q + 63) / 64);
  gemm_out_k<<<g3, 256, 0, stream>>>(fh, fl, outWth, outWtl, outb, out);
}